// Round 6
// baseline (359.243 us; speedup 1.0000x reference)
//
#include <hip/hip_runtime.h>
#include <hip/hip_fp16.h>

#define D 128
#define EPS 1e-5f
#define KB 64          // coarse count/scatter blocks
#define NBSH 7         // bucket = dst >> 7
#define BUCKW 128      // dsts per bucket

typedef unsigned int u32;
typedef unsigned short u16;
typedef unsigned char u8;
typedef __attribute__((ext_vector_type(8))) _Float16 half8;  // mfma A/B frag
typedef __attribute__((ext_vector_type(4))) float f32x4;
typedef __attribute__((ext_vector_type(2))) float f32x2;

__device__ inline u16 f2h(float x) {
  _Float16 t = (_Float16)x;
  return __builtin_bit_cast(u16, t);
}
__device__ inline u8 f2fp8(float x) {
  return (u8)(__builtin_amdgcn_cvt_pk_fp8_f32(x, x, 0, false) & 0xff);
}

// ---------------------------------------------------------------------------
// P0: convert W1,W2 fp32[k][c] -> fp16 Wt[c][k]; block 128 zeroes dhist.
__global__ __launch_bounds__(256) void k_prep(const float* __restrict__ W1,
                                              const float* __restrict__ W2,
                                              u16* __restrict__ Wt1,
                                              u16* __restrict__ Wt2,
                                              int* __restrict__ dhist) {
  if (blockIdx.x < 128) {
    int i = blockIdx.x * 256 + threadIdx.x;
    const float* W = (i < D * D) ? W1 : W2;
    u16* Wt = (i < D * D) ? Wt1 : Wt2;
    int ii = i & (D * D - 1);
    int k = ii >> 7, c = ii & 127;
    Wt[c * D + k] = f2h(W[ii]);
  } else {
    if (threadIdx.x < 64) dhist[threadIdx.x] = 0;
  }
}

// ---------------------------------------------------------------------------
// LDS-free MFMA GEMM body; OUTPUT IS FP8 (e4m3). A-frag from global
// (contiguous 16B in k); B from Wt[c][k] (L2-hot); D: col=ct*16+m, row=q*4+reg.
template <bool F32IN>
__device__ __forceinline__ void gemm_body(const void* __restrict__ in_,
                                          const u16* __restrict__ Wt,
                                          u8* __restrict__ out, int nrows,
                                          int blk) {
  const int tid = threadIdx.x;
  const int lane = tid & 63, wv = tid >> 6;
  const int m = lane & 15, q = lane >> 4;
  const int r0 = blk * 64 + wv * 16;
  const int rowa = min(r0 + m, nrows - 1);

  f32x4 acc[8];
#pragma unroll
  for (int ct = 0; ct < 8; ct++) acc[ct] = (f32x4)(0.0f);

#pragma unroll
  for (int kk = 0; kk < 4; kk++) {
    const int kbase = kk * 32 + q * 8;
    half8 a;
    if (F32IN) {
      const float* in = (const float*)in_;
      float4 v0 = *(const float4*)(in + (size_t)rowa * D + kbase);
      float4 v1 = *(const float4*)(in + (size_t)rowa * D + kbase + 4);
      a[0] = (_Float16)v0.x; a[1] = (_Float16)v0.y;
      a[2] = (_Float16)v0.z; a[3] = (_Float16)v0.w;
      a[4] = (_Float16)v1.x; a[5] = (_Float16)v1.y;
      a[6] = (_Float16)v1.z; a[7] = (_Float16)v1.w;
    } else {
      const u16* in = (const u16*)in_;
      a = *(const half8*)(in + (size_t)rowa * D + kbase);
    }
#pragma unroll
    for (int ct = 0; ct < 8; ct++) {
      half8 b = *(const half8*)(Wt + (ct * 16 + m) * D + kbase);
      acc[ct] = __builtin_amdgcn_mfma_f32_16x16x32_f16(a, b, acc[ct], 0, 0, 0);
    }
  }

#pragma unroll
  for (int ct = 0; ct < 8; ct++) {
#pragma unroll
    for (int rg = 0; rg < 4; rg++) {
      int rr = r0 + q * 4 + rg;
      if (rr < nrows) out[(size_t)rr * D + ct * 16 + m] = f2fp8(acc[ct][rg]);
    }
  }
}

// ph1: coarse-bucket count, 8-deep batched (blocks [0,KB)) || GEMM1.
__global__ __launch_bounds__(256) void k_count_gemm1(
    const int* __restrict__ dst, int* __restrict__ cnt, int E, int NB, int EPB,
    const float* __restrict__ x, const u16* __restrict__ Wt1,
    u8* __restrict__ A, int nrows) {
  if (blockIdx.x < (u32)KB) {
    __shared__ int hist[512];
    const int k = blockIdx.x, tid = threadIdx.x;
    for (int i = tid; i < NB; i += 256) hist[i] = 0;
    __syncthreads();
    const int e0 = k * EPB, e1 = min(E, e0 + EPB);
    for (int base = e0 + tid; base < e1; base += 2048) {
      int dd[8];
#pragma unroll
      for (int i = 0; i < 8; i++) {
        int e = base + i * 256;
        dd[i] = (e < e1) ? dst[e] : -1;
      }
#pragma unroll
      for (int i = 0; i < 8; i++)
        if (dd[i] >= 0) atomicAdd(&hist[dd[i] >> NBSH], 1);
    }
    __syncthreads();
    for (int b = tid; b < NB; b += 256) cnt[b * KB + k] = hist[b];
  } else {
    gemm_body<true>(x, Wt1, A, nrows, blockIdx.x - KB);
  }
}

// ph2a: per-block (1024 elem) reduce -> bsum.
__global__ __launch_bounds__(256) void k_scan_reduce(
    const int* __restrict__ cnt, int M, int* __restrict__ bsum) {
  const int b = blockIdx.x, t = threadIdx.x;
  const int lane = t & 63, w = t >> 6;
  int idx = b * 1024 + t * 4;
  int4 v = make_int4(0, 0, 0, 0);
  if (idx + 3 < M) {
    v = *(const int4*)(cnt + idx);
  } else {
    if (idx + 0 < M) v.x = cnt[idx + 0];
    if (idx + 1 < M) v.y = cnt[idx + 1];
    if (idx + 2 < M) v.z = cnt[idx + 2];
  }
  int s = v.x + v.y + v.z + v.w;
#pragma unroll
  for (int o = 1; o < 64; o <<= 1) s += __shfl_xor(s, o, 64);
  __shared__ int ws[4];
  if (lane == 0) ws[w] = s;
  __syncthreads();
  if (t == 0) bsum[b] = ws[0] + ws[1] + ws[2] + ws[3];
}

// ph2b: per-block local scan; block offset = sum of bsum[0..b-1] (inline mid).
__global__ __launch_bounds__(256) void k_scan_apply(
    int* __restrict__ cnt, int M, const int* __restrict__ bsum,
    int* __restrict__ bsv, int NB, int E) {
  const int b = blockIdx.x, t = threadIdx.x;
  const int lane = t & 63, w = t >> 6;
  if (b == 0 && t == 0) bsv[NB] = E;
  int idx = b * 1024 + t * 4;
  int4 v = make_int4(0, 0, 0, 0);
  if (idx + 3 < M) {
    v = *(const int4*)(cnt + idx);
  } else {
    if (idx + 0 < M) v.x = cnt[idx + 0];
    if (idx + 1 < M) v.y = cnt[idx + 1];
    if (idx + 2 < M) v.z = cnt[idx + 2];
  }
  int s = v.x + v.y + v.z + v.w;
  int incl = s;
#pragma unroll
  for (int o = 1; o < 64; o <<= 1) {
    int u = __shfl_up(incl, o, 64);
    if (lane >= o) incl += u;
  }
  __shared__ int ws[4];
  __shared__ int sboff;
  if (lane == 63) ws[w] = incl;
  if (t < 64) {
    int partial = 0;
    for (int j = t; j < b; j += 64) partial += bsum[j];
#pragma unroll
    for (int o = 32; o >= 1; o >>= 1) partial += __shfl_xor(partial, o, 64);
    if (t == 0) sboff = partial;
  }
  __syncthreads();
  int wbase = 0;
#pragma unroll
  for (int j = 0; j < 4; j++)
    if (j < w) wbase += ws[j];
  int base = sboff + wbase + incl - s;  // exclusive prefix for idx
  int e0 = base, e1 = e0 + v.x, e2 = e1 + v.y, e3 = e2 + v.z;
  // idx is a multiple of 4; only idx itself can be a multiple of KB=64.
  if (idx < M) {
    cnt[idx] = e0;
    if ((idx & (KB - 1)) == 0) bsv[idx >> 6] = e0;
  }
  if (idx + 1 < M) cnt[idx + 1] = e1;
  if (idx + 2 < M) cnt[idx + 2] = e2;
  if (idx + 3 < M) cnt[idx + 3] = e3;
}

// ph3: scatter edges into bucket-grouped tmp via LDS cursors, 8-deep batched.
__global__ __launch_bounds__(256) void k_scatter(
    const int* __restrict__ src, const int* __restrict__ dst,
    const int* __restrict__ cnt, u32* __restrict__ tmp, int E, int NB,
    int EPB) {
  __shared__ int off[512];
  const int k = blockIdx.x, tid = threadIdx.x;
  for (int b = tid; b < NB; b += 256) off[b] = cnt[b * KB + k];
  __syncthreads();
  const int e0 = k * EPB, e1 = min(E, e0 + EPB);
  for (int base = e0 + tid; base < e1; base += 2048) {
    int dd[8], ss[8];
#pragma unroll
    for (int i = 0; i < 8; i++) {
      int e = base + i * 256;
      dd[i] = (e < e1) ? dst[e] : -1;
      ss[i] = (e < e1) ? src[e] : 0;
    }
#pragma unroll
    for (int i = 0; i < 8; i++) {
      if (dd[i] >= 0) {
        int p = atomicAdd(&off[dd[i] >> NBSH], 1);
        tmp[p] = (u32)ss[i] | ((u32)(dd[i] & (BUCKW - 1)) << 16);
      }
    }
  }
}

// ph4: one block per bucket: fine 128-bin LDS hist + scan -> deg/dinv/meta,
// then dst-sorted csr (entry = src); also 64-bin degree histogram -> dhist.
__global__ __launch_bounds__(256) void k_bucket(
    const u32* __restrict__ tmp, const int* __restrict__ bsv,
    int4* __restrict__ meta, float* __restrict__ dinv,
    u32* __restrict__ csr, int* __restrict__ dhist, int N) {
  __shared__ int hist[BUCKW];
  __shared__ int sc[BUCKW];
  __shared__ int cur[BUCKW];
  __shared__ int dh[64];
  const int b = blockIdx.x, tid = threadIdx.x;
  const int s0 = bsv[b], s1 = bsv[b + 1];
  if (tid < BUCKW) hist[tid] = 0;
  if (tid >= BUCKW && tid < BUCKW + 64) dh[tid - BUCKW] = 0;
  __syncthreads();
  for (int base = s0 + tid; base < s1; base += 1024) {
    int tt[4];
#pragma unroll
    for (int i = 0; i < 4; i++) {
      int idx = base + i * 256;
      tt[i] = (idx < s1) ? (int)tmp[idx] : -1;
    }
#pragma unroll
    for (int i = 0; i < 4; i++)
      if (tt[i] >= 0) atomicAdd(&hist[(tt[i] >> 16) & (BUCKW - 1)], 1);
  }
  __syncthreads();
  if (tid < BUCKW) sc[tid] = hist[tid];
  __syncthreads();
#pragma unroll
  for (int o = 1; o < BUCKW; o <<= 1) {
    int t = 0;
    if (tid < BUCKW && tid >= o) t = sc[tid - o];
    __syncthreads();
    if (tid < BUCKW) sc[tid] += t;
    __syncthreads();
  }
  if (tid < BUCKW) {
    int dg = hist[tid];
    int excl = sc[tid] - dg;
    cur[tid] = excl;
    int d = (b << NBSH) + tid;
    if (d < N) {
      float dv = rsqrtf((float)dg + 1.0f);
      meta[d] = make_int4(s0 + excl, dg, __builtin_bit_cast(int, dv), 0);
      dinv[d] = dv;
      atomicAdd(&dh[min(dg, 63)], 1);
    }
  }
  __syncthreads();
  if (tid < 64 && dh[tid] > 0) atomicAdd(&dhist[tid], dh[tid]);
  for (int base = s0 + tid; base < s1; base += 1024) {
    int tt[4];
#pragma unroll
    for (int i = 0; i < 4; i++) {
      int idx = base + i * 256;
      tt[i] = (idx < s1) ? (int)tmp[idx] : -1;
    }
#pragma unroll
    for (int i = 0; i < 4; i++) {
      if (tt[i] >= 0) {
        int r = atomicAdd(&cur[(tt[i] >> 16) & (BUCKW - 1)], 1);
        csr[s0 + r] = (u32)tt[i] & 0xffffu;
      }
    }
  }
}

// ph4b: exclusive scan of 64-bin degree hist -> bincur (ascending degree).
__global__ __launch_bounds__(64) void k_binscan(const int* __restrict__ dhist,
                                                int* __restrict__ bincur) {
  const int t = threadIdx.x;
  int v = dhist[t];
  int incl = v;
#pragma unroll
  for (int o = 1; o < 64; o <<= 1) {
    int u = __shfl_up(incl, o, 64);
    if (t >= o) incl += u;
  }
  bincur[t] = incl - v;
}

// ph5: pack weights: csr entry src -> src | fp16(dinv[s]*dinv[d])<<16;
// j0==0 thread also places row into degree-sorted perm.
__global__ __launch_bounds__(256) void k_weights(
    const int4* __restrict__ meta, const float* __restrict__ dinv,
    u32* __restrict__ csr, int* __restrict__ bincur, int* __restrict__ perm,
    int N) {
  int gid = blockIdx.x * 256 + threadIdx.x;
  int r = gid >> 2, j0 = gid & 3;
  if (r >= N) return;
  int4 mt = meta[r];
  if (j0 == 0) {
    int slot = atomicAdd(&bincur[min(mt.y, 63)], 1);
    perm[slot] = r;
  }
  float dv = __builtin_bit_cast(float, mt.z);
  for (int j = j0; j < mt.y; j += 4) {
    u32 s = csr[mt.x + j];
    float w = dinv[s] * dv;
    csr[mt.x + j] = s | ((u32)f2h(w) << 16);
  }
}

// ---------------------------------------------------------------------------
// Gather+LN core — FP8 h rows (128 B), fp32 accumulation.
// Row owned by 16 lanes, uint2 (8 fp8) per lane.
// csr entries fetched as UNIFORM per-group vector loads (HW broadcast);
// callers pass degree-sorted rows so wave-max degree ~= row degree.
#define ACC_EDGE(vv, ee)                                                     \
  {                                                                          \
    float ww = (float)__builtin_bit_cast(_Float16, (u16)((ee) >> 16));       \
    f32x2 p_;                                                                \
    p_ = __builtin_amdgcn_cvt_pk_f32_fp8(vv.x, false);                       \
    acc[0] = fmaf(p_[0], ww, acc[0]); acc[1] = fmaf(p_[1], ww, acc[1]);      \
    p_ = __builtin_amdgcn_cvt_pk_f32_fp8(vv.x, true);                        \
    acc[2] = fmaf(p_[0], ww, acc[2]); acc[3] = fmaf(p_[1], ww, acc[3]);      \
    p_ = __builtin_amdgcn_cvt_pk_f32_fp8(vv.y, false);                       \
    acc[4] = fmaf(p_[0], ww, acc[4]); acc[5] = fmaf(p_[1], ww, acc[5]);      \
    p_ = __builtin_amdgcn_cvt_pk_f32_fp8(vv.y, true);                        \
    acc[6] = fmaf(p_[0], ww, acc[6]); acc[7] = fmaf(p_[1], ww, acc[7]);      \
  }

__device__ __forceinline__ void gather_ln_core(
    const uint2* __restrict__ hb, const int4* __restrict__ meta,
    const u32* __restrict__ csr, const float* __restrict__ b,
    const float* __restrict__ g, const float* __restrict__ bln,
    int row, int n, int sl, float out[8]) {
  const bool valid = row < n;
  const int rc = valid ? row : 0;
  int4 mt = meta[rc];
  int beg = mt.x;
  int cnt = valid ? mt.y : 0;
  float dv = __builtin_bit_cast(float, mt.z);
  float sn = dv * dv;

  float acc[8];
  {
    uint2 su = hb[(size_t)rc * 16 + sl];
    f32x2 p0 = __builtin_amdgcn_cvt_pk_f32_fp8(su.x, false);
    f32x2 p1 = __builtin_amdgcn_cvt_pk_f32_fp8(su.x, true);
    f32x2 p2 = __builtin_amdgcn_cvt_pk_f32_fp8(su.y, false);
    f32x2 p3 = __builtin_amdgcn_cvt_pk_f32_fp8(su.y, true);
    acc[0] = p0[0] * sn; acc[1] = p0[1] * sn;
    acc[2] = p1[0] * sn; acc[3] = p1[1] * sn;
    acc[4] = p2[0] * sn; acc[5] = p2[1] * sn;
    acc[6] = p3[0] * sn; acc[7] = p3[1] * sn;
  }

  int cm = max(cnt, __shfl_xor(cnt, 16, 64));
  cm = max(cm, __shfl_xor(cm, 32, 64));

  for (int j0 = 0; j0 < cm; j0 += 8) {
    u32 e[8];
#pragma unroll
    for (int jj = 0; jj < 8; jj++) {
      int j = j0 + jj;
      e[jj] = (j < cnt) ? csr[beg + j] : 0u;   // uniform per 16-lane group
    }
    uint2 v[8];
#pragma unroll
    for (int jj = 0; jj < 8; jj++)
      v[jj] = hb[(size_t)(e[jj] & 0xffffu) * 16 + sl];
#pragma unroll
    for (int jj = 0; jj < 8; jj++) ACC_EDGE(v[jj], e[jj]);
  }

  // ---- LayerNorm over 128 cols, 8 per lane across 16 lanes ----
  int d0 = sl * 8;
  float4 bb0 = *(const float4*)(b + d0);
  float4 bb1 = *(const float4*)(b + d0 + 4);
  float a0 = acc[0] + bb0.x, a1 = acc[1] + bb0.y;
  float a2 = acc[2] + bb0.z, a3 = acc[3] + bb0.w;
  float a4 = acc[4] + bb1.x, a5 = acc[5] + bb1.y;
  float a6 = acc[6] + bb1.z, a7 = acc[7] + bb1.w;

  float sum = ((a0 + a1) + (a2 + a3)) + ((a4 + a5) + (a6 + a7));
#pragma unroll
  for (int o = 8; o >= 1; o >>= 1) sum += __shfl_xor(sum, o, 16);
  float mu = sum * (1.0f / 128.0f);
  float e0 = a0 - mu, e1 = a1 - mu, e2 = a2 - mu, e3 = a3 - mu;
  float e4 = a4 - mu, e5 = a5 - mu, e6 = a6 - mu, e7 = a7 - mu;
  float vs = ((e0 * e0 + e1 * e1) + (e2 * e2 + e3 * e3)) +
             ((e4 * e4 + e5 * e5) + (e6 * e6 + e7 * e7));
#pragma unroll
  for (int o = 8; o >= 1; o >>= 1) vs += __shfl_xor(vs, o, 16);
  float inv = rsqrtf(vs * (1.0f / 128.0f) + EPS);

  float4 gg0 = *(const float4*)(g + d0);
  float4 gg1 = *(const float4*)(g + d0 + 4);
  float4 bl0 = *(const float4*)(bln + d0);
  float4 bl1 = *(const float4*)(bln + d0 + 4);
  out[0] = fmaxf(e0 * inv * gg0.x + bl0.x, 0.0f);
  out[1] = fmaxf(e1 * inv * gg0.y + bl0.y, 0.0f);
  out[2] = fmaxf(e2 * inv * gg0.z + bl0.z, 0.0f);
  out[3] = fmaxf(e3 * inv * gg0.w + bl0.w, 0.0f);
  out[4] = fmaxf(e4 * inv * gg1.x + bl1.x, 0.0f);
  out[5] = fmaxf(e5 * inv * gg1.y + bl1.y, 0.0f);
  out[6] = fmaxf(e6 * inv * gg1.z + bl1.z, 0.0f);
  out[7] = fmaxf(e7 * inv * gg1.w + bl1.w, 0.0f);
}

// P6a: pure gather1 + LN + ReLU -> y1 (fp16) in global. Rows via perm
// (degree-sorted) for wave/block load balance.
__global__ __launch_bounds__(256, 8) void k_gather1(
    const uint2* __restrict__ hb, const int4* __restrict__ meta,
    const u32* __restrict__ csr, const int* __restrict__ perm,
    const float* __restrict__ b, const float* __restrict__ g,
    const float* __restrict__ bln,
    u16* __restrict__ y1, int n) {
  const int tid = threadIdx.x;
  const int sl = tid & 15;
  const int pr = blockIdx.x * 16 + (tid >> 4);
  const int row = (pr < n) ? perm[pr] : n;
  float o[8];
  gather_ln_core(hb, meta, csr, b, g, bln, row, n, sl, o);
  if (pr >= n) return;
  uint4 pk;
  pk.x = ((u32)f2h(o[1]) << 16) | (u32)f2h(o[0]);
  pk.y = ((u32)f2h(o[3]) << 16) | (u32)f2h(o[2]);
  pk.z = ((u32)f2h(o[5]) << 16) | (u32)f2h(o[4]);
  pk.w = ((u32)f2h(o[7]) << 16) | (u32)f2h(o[6]);
  *(uint4*)(y1 + (size_t)row * D + sl * 8) = pk;
}

// P6b: standalone GEMM2: y1 (fp16) @ W2 -> B (h2, fp8).
__global__ __launch_bounds__(256) void k_gemm2(const u16* __restrict__ y1,
                                               const u16* __restrict__ Wt2,
                                               u8* __restrict__ outB, int n) {
  gemm_body<false>(y1, Wt2, outB, n, blockIdx.x);
}

// P7: gather2 + LN + ReLU + residual -> fp32 out. Rows via perm.
__global__ __launch_bounds__(256, 8) void k_gather2(
    const uint2* __restrict__ hb, const int4* __restrict__ meta,
    const u32* __restrict__ csr, const int* __restrict__ perm,
    const float* __restrict__ b, const float* __restrict__ g,
    const float* __restrict__ bln, const float* __restrict__ resid,
    float* __restrict__ outf, int n) {
  const int tid = threadIdx.x;
  const int sl = tid & 15;
  const int pr = blockIdx.x * 16 + (tid >> 4);
  const int row = (pr < n) ? perm[pr] : n;
  float o[8];
  gather_ln_core(hb, meta, csr, b, g, bln, row, n, sl, o);
  if (pr >= n) return;
  size_t base = (size_t)row * D + sl * 8;
  float4 r0 = *(const float4*)(resid + base);
  float4 r1 = *(const float4*)(resid + base + 4);
  *(float4*)(outf + base) =
      make_float4(o[0] + r0.x, o[1] + r0.y, o[2] + r0.z, o[3] + r0.w);
  *(float4*)(outf + base + 4) =
      make_float4(o[4] + r1.x, o[5] + r1.y, o[6] + r1.z, o[7] + r1.w);
}

// ---------------------------------------------------------------------------
extern "C" void kernel_launch(void* const* d_in, const int* in_sizes, int n_in,
                              void* d_out, int out_size, void* d_ws, size_t ws_size,
                              hipStream_t stream) {
  const float* x    = (const float*)d_in[0];
  const int*   ei   = (const int*)d_in[1];
  const float* W1   = (const float*)d_in[2];
  const float* b1   = (const float*)d_in[3];
  const float* g1   = (const float*)d_in[4];
  const float* bl1  = (const float*)d_in[5];
  const float* W2   = (const float*)d_in[6];
  const float* b2   = (const float*)d_in[7];
  const float* g2   = (const float*)d_in[8];
  const float* bl2  = (const float*)d_in[9];

  const int N = in_sizes[0] / D;
  const int E = in_sizes[1] / 2;
  const int* src = ei;
  const int* dst = ei + E;

  const int NB  = (N + BUCKW - 1) / BUCKW;  // coarse buckets
  const int M   = NB * KB;
  const int EPB = (E + KB - 1) / KB;        // edges per count/scatter block
  const int GB  = (N + 63) / 64;            // gemm blocks
  const int RB  = (N + 15) / 16;            // gather blocks (16 rows each)
  const int SB  = (M + 1023) / 1024;        // scan blocks

  size_t off = 0;
  auto walloc = [&](size_t bytes) {
    void* p = (char*)d_ws + off;
    off = (off + bytes + 255) & ~(size_t)255;
    return p;
  };
  int*   cnt   = (int*)walloc((size_t)M * 4);
  int*   bsum  = (int*)walloc((size_t)SB * 4);
  int*   bsv   = (int*)walloc((size_t)(NB + 1) * 4);
  int*   dhist = (int*)walloc(64 * 4);
  int*   bincur= (int*)walloc(64 * 4);
  int*   perm  = (int*)walloc((size_t)N * 4);
  u32*   tmp   = (u32*)walloc((size_t)E * 4);
  u32*   csr   = (u32*)walloc((size_t)E * 4);
  int4*  meta  = (int4*)walloc((size_t)N * 16);
  float* dinv  = (float*)walloc((size_t)N * 4);
  u8*    A     = (u8*)walloc((size_t)N * D);        // h1 (fp8 e4m3)
  u8*    B     = (u8*)walloc((size_t)N * D);        // h2 (fp8 e4m3)
  u16*   Wt1   = (u16*)walloc((size_t)D * D * 2);
  u16*   Wt2   = (u16*)walloc((size_t)D * D * 2);
  u16*   y1    = (u16*)walloc((size_t)N * D * 2);   // LN1 out (fp16)
  float* O     = (float*)d_out;

  // P0: weight converts + dhist zero
  k_prep<<<129, 256, 0, stream>>>(W1, W2, Wt1, Wt2, dhist);
  // ph1: coarse count || GEMM1 (x @ W1 -> A fp8)
  k_count_gemm1<<<KB + GB, 256, 0, stream>>>(dst, cnt, E, NB, EPB, x, Wt1, A, N);
  // ph2: parallel scan (reduce -> apply-with-inline-mid)
  k_scan_reduce<<<SB, 256, 0, stream>>>(cnt, M, bsum);
  k_scan_apply<<<SB, 256, 0, stream>>>(cnt, M, bsum, bsv, NB, E);
  // ph3: scatter into buckets
  k_scatter<<<KB, 256, 0, stream>>>(src, dst, cnt, tmp, E, NB, EPB);
  // ph4: per-bucket fine sort -> csr + meta + dinv + degree hist
  k_bucket<<<NB, 256, 0, stream>>>(tmp, bsv, meta, dinv, csr, dhist, N);
  // ph4b: degree-bin scan
  k_binscan<<<1, 64, 0, stream>>>(dhist, bincur);
  // ph5: pack weights + build degree-sorted perm
  k_weights<<<(N * 4 + 255) / 256, 256, 0, stream>>>(meta, dinv, csr, bincur,
                                                     perm, N);
  // P6a: gather1 + LN + ReLU -> y1 (fp16)
  k_gather1<<<RB, 256, 0, stream>>>((const uint2*)A, meta, csr, perm,
                                    b1, g1, bl1, y1, N);
  // P6b: GEMM2 -> B (fp8)
  k_gemm2<<<GB, 256, 0, stream>>>(y1, Wt2, B, N);
  // P7: gather2 + LN + ReLU + residual -> O
  k_gather2<<<RB, 256, 0, stream>>>((const uint2*)B, meta, csr, perm,
                                    b2, g2, bl2, x, O, N);
}

// Round 7
// 198.982 us; speedup vs baseline: 1.8054x; 1.8054x over previous
//
#include <hip/hip_runtime.h>
#include <hip/hip_fp16.h>

#define D 128
#define EPS 1e-5f
#define KB 64          // coarse count/scatter blocks
#define NBSH 7         // bucket = dst >> 7
#define BUCKW 128      // dsts per bucket

typedef unsigned int u32;
typedef unsigned short u16;
typedef unsigned char u8;
typedef __attribute__((ext_vector_type(8))) _Float16 half8;  // mfma A/B frag
typedef __attribute__((ext_vector_type(4))) float f32x4;
typedef __attribute__((ext_vector_type(2))) float f32x2;

__device__ inline u16 f2h(float x) {
  _Float16 t = (_Float16)x;
  return __builtin_bit_cast(u16, t);
}
__device__ inline u8 f2fp8(float x) {
  return (u8)(__builtin_amdgcn_cvt_pk_fp8_f32(x, x, 0, false) & 0xff);
}

// ---------------------------------------------------------------------------
// P0: convert W1,W2 fp32[k][c] -> fp16 Wt[c][k].
__global__ __launch_bounds__(256) void k_prep(const float* __restrict__ W1,
                                              const float* __restrict__ W2,
                                              u16* __restrict__ Wt1,
                                              u16* __restrict__ Wt2) {
  int i = blockIdx.x * 256 + threadIdx.x;
  if (i < 2 * D * D) {
    const float* W = (i < D * D) ? W1 : W2;
    u16* Wt = (i < D * D) ? Wt1 : Wt2;
    int ii = i & (D * D - 1);
    int k = ii >> 7, c = ii & 127;
    Wt[c * D + k] = f2h(W[ii]);
  }
}

// ---------------------------------------------------------------------------
// LDS-free MFMA GEMM body; OUTPUT IS FP8 (e4m3). A-frag from global
// (contiguous 16B in k); B from Wt[c][k] (L2-hot); D: col=ct*16+m, row=q*4+reg.
template <bool F32IN>
__device__ __forceinline__ void gemm_body(const void* __restrict__ in_,
                                          const u16* __restrict__ Wt,
                                          u8* __restrict__ out, int nrows,
                                          int blk) {
  const int tid = threadIdx.x;
  const int lane = tid & 63, wv = tid >> 6;
  const int m = lane & 15, q = lane >> 4;
  const int r0 = blk * 64 + wv * 16;
  const int rowa = min(r0 + m, nrows - 1);

  f32x4 acc[8];
#pragma unroll
  for (int ct = 0; ct < 8; ct++) acc[ct] = (f32x4)(0.0f);

#pragma unroll
  for (int kk = 0; kk < 4; kk++) {
    const int kbase = kk * 32 + q * 8;
    half8 a;
    if (F32IN) {
      const float* in = (const float*)in_;
      float4 v0 = *(const float4*)(in + (size_t)rowa * D + kbase);
      float4 v1 = *(const float4*)(in + (size_t)rowa * D + kbase + 4);
      a[0] = (_Float16)v0.x; a[1] = (_Float16)v0.y;
      a[2] = (_Float16)v0.z; a[3] = (_Float16)v0.w;
      a[4] = (_Float16)v1.x; a[5] = (_Float16)v1.y;
      a[6] = (_Float16)v1.z; a[7] = (_Float16)v1.w;
    } else {
      const u16* in = (const u16*)in_;
      a = *(const half8*)(in + (size_t)rowa * D + kbase);
    }
#pragma unroll
    for (int ct = 0; ct < 8; ct++) {
      half8 b = *(const half8*)(Wt + (ct * 16 + m) * D + kbase);
      acc[ct] = __builtin_amdgcn_mfma_f32_16x16x32_f16(a, b, acc[ct], 0, 0, 0);
    }
  }

#pragma unroll
  for (int ct = 0; ct < 8; ct++) {
#pragma unroll
    for (int rg = 0; rg < 4; rg++) {
      int rr = r0 + q * 4 + rg;
      if (rr < nrows) out[(size_t)rr * D + ct * 16 + m] = f2fp8(acc[ct][rg]);
    }
  }
}

// ph1: coarse-bucket count, 8-deep batched (blocks [0,KB)) || GEMM1.
__global__ __launch_bounds__(256) void k_count_gemm1(
    const int* __restrict__ dst, int* __restrict__ cnt, int E, int NB, int EPB,
    const float* __restrict__ x, const u16* __restrict__ Wt1,
    u8* __restrict__ A, int nrows) {
  if (blockIdx.x < (u32)KB) {
    __shared__ int hist[512];
    const int k = blockIdx.x, tid = threadIdx.x;
    for (int i = tid; i < NB; i += 256) hist[i] = 0;
    __syncthreads();
    const int e0 = k * EPB, e1 = min(E, e0 + EPB);
    for (int base = e0 + tid; base < e1; base += 2048) {
      int dd[8];
#pragma unroll
      for (int i = 0; i < 8; i++) {
        int e = base + i * 256;
        dd[i] = (e < e1) ? dst[e] : -1;
      }
#pragma unroll
      for (int i = 0; i < 8; i++)
        if (dd[i] >= 0) atomicAdd(&hist[dd[i] >> NBSH], 1);
    }
    __syncthreads();
    for (int b = tid; b < NB; b += 256) cnt[b * KB + k] = hist[b];
  } else {
    gemm_body<true>(x, Wt1, A, nrows, blockIdx.x - KB);
  }
}

// ph2a: per-block (1024 elem) reduce -> bsum.
__global__ __launch_bounds__(256) void k_scan_reduce(
    const int* __restrict__ cnt, int M, int* __restrict__ bsum) {
  const int b = blockIdx.x, t = threadIdx.x;
  const int lane = t & 63, w = t >> 6;
  int idx = b * 1024 + t * 4;
  int4 v = make_int4(0, 0, 0, 0);
  if (idx + 3 < M) {
    v = *(const int4*)(cnt + idx);
  } else {
    if (idx + 0 < M) v.x = cnt[idx + 0];
    if (idx + 1 < M) v.y = cnt[idx + 1];
    if (idx + 2 < M) v.z = cnt[idx + 2];
  }
  int s = v.x + v.y + v.z + v.w;
#pragma unroll
  for (int o = 1; o < 64; o <<= 1) s += __shfl_xor(s, o, 64);
  __shared__ int ws[4];
  if (lane == 0) ws[w] = s;
  __syncthreads();
  if (t == 0) bsum[b] = ws[0] + ws[1] + ws[2] + ws[3];
}

// ph2b: per-block local scan; block offset = sum of bsum[0..b-1] (inline mid).
__global__ __launch_bounds__(256) void k_scan_apply(
    int* __restrict__ cnt, int M, const int* __restrict__ bsum,
    int* __restrict__ bsv, int NB, int E) {
  const int b = blockIdx.x, t = threadIdx.x;
  const int lane = t & 63, w = t >> 6;
  if (b == 0 && t == 0) bsv[NB] = E;
  int idx = b * 1024 + t * 4;
  int4 v = make_int4(0, 0, 0, 0);
  if (idx + 3 < M) {
    v = *(const int4*)(cnt + idx);
  } else {
    if (idx + 0 < M) v.x = cnt[idx + 0];
    if (idx + 1 < M) v.y = cnt[idx + 1];
    if (idx + 2 < M) v.z = cnt[idx + 2];
  }
  int s = v.x + v.y + v.z + v.w;
  int incl = s;
#pragma unroll
  for (int o = 1; o < 64; o <<= 1) {
    int u = __shfl_up(incl, o, 64);
    if (lane >= o) incl += u;
  }
  __shared__ int ws[4];
  __shared__ int sboff;
  if (lane == 63) ws[w] = incl;
  if (t < 64) {
    int partial = 0;
    for (int j = t; j < b; j += 64) partial += bsum[j];
#pragma unroll
    for (int o = 32; o >= 1; o >>= 1) partial += __shfl_xor(partial, o, 64);
    if (t == 0) sboff = partial;
  }
  __syncthreads();
  int wbase = 0;
#pragma unroll
  for (int j = 0; j < 4; j++)
    if (j < w) wbase += ws[j];
  int base = sboff + wbase + incl - s;  // exclusive prefix for idx
  int e0 = base, e1 = e0 + v.x, e2 = e1 + v.y, e3 = e2 + v.z;
  // idx is a multiple of 4; only idx itself can be a multiple of KB=64.
  if (idx < M) {
    cnt[idx] = e0;
    if ((idx & (KB - 1)) == 0) bsv[idx >> 6] = e0;
  }
  if (idx + 1 < M) cnt[idx + 1] = e1;
  if (idx + 2 < M) cnt[idx + 2] = e2;
  if (idx + 3 < M) cnt[idx + 3] = e3;
}

// ph3: scatter edges into bucket-grouped tmp via LDS cursors, 8-deep batched.
__global__ __launch_bounds__(256) void k_scatter(
    const int* __restrict__ src, const int* __restrict__ dst,
    const int* __restrict__ cnt, u32* __restrict__ tmp, int E, int NB,
    int EPB) {
  __shared__ int off[512];
  const int k = blockIdx.x, tid = threadIdx.x;
  for (int b = tid; b < NB; b += 256) off[b] = cnt[b * KB + k];
  __syncthreads();
  const int e0 = k * EPB, e1 = min(E, e0 + EPB);
  for (int base = e0 + tid; base < e1; base += 2048) {
    int dd[8], ss[8];
#pragma unroll
    for (int i = 0; i < 8; i++) {
      int e = base + i * 256;
      dd[i] = (e < e1) ? dst[e] : -1;
      ss[i] = (e < e1) ? src[e] : 0;
    }
#pragma unroll
    for (int i = 0; i < 8; i++) {
      if (dd[i] >= 0) {
        int p = atomicAdd(&off[dd[i] >> NBSH], 1);
        tmp[p] = (u32)ss[i] | ((u32)(dd[i] & (BUCKW - 1)) << 16);
      }
    }
  }
}

// ph4: one block per bucket: fine 128-bin LDS hist + scan -> deg/dinv/meta,
// then dst-sorted csr (entry = src); writes per-bucket 64-bin degree hist
// to bc[b*64+bin] (NO global atomics).
__global__ __launch_bounds__(256) void k_bucket(
    const u32* __restrict__ tmp, const int* __restrict__ bsv,
    int4* __restrict__ meta, float* __restrict__ dinv,
    u32* __restrict__ csr, int* __restrict__ bc, int N) {
  __shared__ int hist[BUCKW];
  __shared__ int sc[BUCKW];
  __shared__ int cur[BUCKW];
  __shared__ int dh[64];
  const int b = blockIdx.x, tid = threadIdx.x;
  const int s0 = bsv[b], s1 = bsv[b + 1];
  if (tid < BUCKW) hist[tid] = 0;
  if (tid >= BUCKW && tid < BUCKW + 64) dh[tid - BUCKW] = 0;
  __syncthreads();
  for (int base = s0 + tid; base < s1; base += 1024) {
    int tt[4];
#pragma unroll
    for (int i = 0; i < 4; i++) {
      int idx = base + i * 256;
      tt[i] = (idx < s1) ? (int)tmp[idx] : -1;
    }
#pragma unroll
    for (int i = 0; i < 4; i++)
      if (tt[i] >= 0) atomicAdd(&hist[(tt[i] >> 16) & (BUCKW - 1)], 1);
  }
  __syncthreads();
  if (tid < BUCKW) sc[tid] = hist[tid];
  __syncthreads();
#pragma unroll
  for (int o = 1; o < BUCKW; o <<= 1) {
    int t = 0;
    if (tid < BUCKW && tid >= o) t = sc[tid - o];
    __syncthreads();
    if (tid < BUCKW) sc[tid] += t;
    __syncthreads();
  }
  if (tid < BUCKW) {
    int dg = hist[tid];
    int excl = sc[tid] - dg;
    cur[tid] = excl;
    int d = (b << NBSH) + tid;
    if (d < N) {
      float dv = rsqrtf((float)dg + 1.0f);
      meta[d] = make_int4(s0 + excl, dg, __builtin_bit_cast(int, dv), 0);
      dinv[d] = dv;
      atomicAdd(&dh[min(dg, 63)], 1);  // LDS only
    }
  }
  __syncthreads();
  if (tid < 64) bc[b * 64 + tid] = dh[tid];
  for (int base = s0 + tid; base < s1; base += 1024) {
    int tt[4];
#pragma unroll
    for (int i = 0; i < 4; i++) {
      int idx = base + i * 256;
      tt[i] = (idx < s1) ? (int)tmp[idx] : -1;
    }
#pragma unroll
    for (int i = 0; i < 4; i++) {
      if (tt[i] >= 0) {
        int r = atomicAdd(&cur[(tt[i] >> 16) & (BUCKW - 1)], 1);
        csr[s0 + r] = (u32)tt[i] & 0xffffu;
      }
    }
  }
}

// ph4b: one block per bin: scan bc[*][bin] over NBK buckets -> pboff
// (within-bin exclusive offsets) + bintot[bin]. No contention.
__global__ __launch_bounds__(256) void k_permscan(
    const int* __restrict__ bc, int* __restrict__ pboff,
    int* __restrict__ bintot, int NBK) {
  const int bin = blockIdx.x, t = threadIdx.x;
  const int lane = t & 63, w = t >> 6;
  __shared__ int ws[4];
  int running = 0;
  for (int c0 = 0; c0 < NBK; c0 += 256) {
    int j = c0 + t;
    int v = (j < NBK) ? bc[j * 64 + bin] : 0;
    int incl = v;
#pragma unroll
    for (int o = 1; o < 64; o <<= 1) {
      int u = __shfl_up(incl, o, 64);
      if (lane >= o) incl += u;
    }
    if (lane == 63) ws[w] = incl;
    __syncthreads();
    int woff = 0, total = 0;
#pragma unroll
    for (int q = 0; q < 4; q++) {
      int tq = ws[q];
      if (q < w) woff += tq;
      total += tq;
    }
    if (j < NBK) pboff[j * 64 + bin] = running + woff + incl - v;
    running += total;
    __syncthreads();
  }
  if (t == 0) bintot[bin] = running;
}

// ph4c: exclusive scan of bintot -> binbase.
__global__ __launch_bounds__(64) void k_binscan(const int* __restrict__ bintot,
                                                int* __restrict__ binbase) {
  const int t = threadIdx.x;
  int v = bintot[t];
  int incl = v;
#pragma unroll
  for (int o = 1; o < 64; o <<= 1) {
    int u = __shfl_up(incl, o, 64);
    if (t >= o) incl += u;
  }
  binbase[t] = incl - v;
}

// ph5: one block per bucket (512 thr, 4/row): pack weights + place rows into
// degree-sorted perm via LDS rank counters (slot = binbase+pboff+lrank).
__global__ __launch_bounds__(512) void k_weights(
    const int4* __restrict__ meta, const float* __restrict__ dinv,
    u32* __restrict__ csr, const int* __restrict__ pboff,
    const int* __restrict__ binbase, int* __restrict__ perm, int N) {
  __shared__ int lcnt[64];
  const int b = blockIdx.x, tid = threadIdx.x;
  if (tid < 64) lcnt[tid] = 0;
  __syncthreads();
  int r = b * BUCKW + (tid >> 2), j0 = tid & 3;
  if (r < N) {
    int4 mt = meta[r];
    if (j0 == 0) {
      int bin = min(mt.y, 63);
      int lrank = atomicAdd(&lcnt[bin], 1);  // LDS only
      perm[binbase[bin] + pboff[b * 64 + bin] + lrank] = r;
    }
    float dv = __builtin_bit_cast(float, mt.z);
    for (int j = j0; j < mt.y; j += 4) {
      u32 s = csr[mt.x + j];
      float w = dinv[s] * dv;
      csr[mt.x + j] = s | ((u32)f2h(w) << 16);
    }
  }
}

// ---------------------------------------------------------------------------
// Gather+LN core — FP8 h rows (128 B), fp32 accumulation.
// Row owned by 16 lanes, uint2 (8 fp8) per lane.
// csr entries fetched as UNIFORM per-group vector loads (HW broadcast);
// callers pass degree-sorted rows so wave-max degree ~= row degree.
#define ACC_EDGE(vv, ee)                                                     \
  {                                                                          \
    float ww = (float)__builtin_bit_cast(_Float16, (u16)((ee) >> 16));       \
    f32x2 p_;                                                                \
    p_ = __builtin_amdgcn_cvt_pk_f32_fp8(vv.x, false);                       \
    acc[0] = fmaf(p_[0], ww, acc[0]); acc[1] = fmaf(p_[1], ww, acc[1]);      \
    p_ = __builtin_amdgcn_cvt_pk_f32_fp8(vv.x, true);                        \
    acc[2] = fmaf(p_[0], ww, acc[2]); acc[3] = fmaf(p_[1], ww, acc[3]);      \
    p_ = __builtin_amdgcn_cvt_pk_f32_fp8(vv.y, false);                       \
    acc[4] = fmaf(p_[0], ww, acc[4]); acc[5] = fmaf(p_[1], ww, acc[5]);      \
    p_ = __builtin_amdgcn_cvt_pk_f32_fp8(vv.y, true);                        \
    acc[6] = fmaf(p_[0], ww, acc[6]); acc[7] = fmaf(p_[1], ww, acc[7]);      \
  }

__device__ __forceinline__ void gather_ln_core(
    const uint2* __restrict__ hb, const int4* __restrict__ meta,
    const u32* __restrict__ csr, const float* __restrict__ b,
    const float* __restrict__ g, const float* __restrict__ bln,
    int row, int n, int sl, float out[8]) {
  const bool valid = row < n;
  const int rc = valid ? row : 0;
  int4 mt = meta[rc];
  int beg = mt.x;
  int cnt = valid ? mt.y : 0;
  float dv = __builtin_bit_cast(float, mt.z);
  float sn = dv * dv;

  float acc[8];
  {
    uint2 su = hb[(size_t)rc * 16 + sl];
    f32x2 p0 = __builtin_amdgcn_cvt_pk_f32_fp8(su.x, false);
    f32x2 p1 = __builtin_amdgcn_cvt_pk_f32_fp8(su.x, true);
    f32x2 p2 = __builtin_amdgcn_cvt_pk_f32_fp8(su.y, false);
    f32x2 p3 = __builtin_amdgcn_cvt_pk_f32_fp8(su.y, true);
    acc[0] = p0[0] * sn; acc[1] = p0[1] * sn;
    acc[2] = p1[0] * sn; acc[3] = p1[1] * sn;
    acc[4] = p2[0] * sn; acc[5] = p2[1] * sn;
    acc[6] = p3[0] * sn; acc[7] = p3[1] * sn;
  }

  int cm = max(cnt, __shfl_xor(cnt, 16, 64));
  cm = max(cm, __shfl_xor(cm, 32, 64));

  for (int j0 = 0; j0 < cm; j0 += 8) {
    u32 e[8];
#pragma unroll
    for (int jj = 0; jj < 8; jj++) {
      int j = j0 + jj;
      e[jj] = (j < cnt) ? csr[beg + j] : 0u;   // uniform per 16-lane group
    }
    uint2 v[8];
#pragma unroll
    for (int jj = 0; jj < 8; jj++)
      v[jj] = hb[(size_t)(e[jj] & 0xffffu) * 16 + sl];
#pragma unroll
    for (int jj = 0; jj < 8; jj++) ACC_EDGE(v[jj], e[jj]);
  }

  // ---- LayerNorm over 128 cols, 8 per lane across 16 lanes ----
  int d0 = sl * 8;
  float4 bb0 = *(const float4*)(b + d0);
  float4 bb1 = *(const float4*)(b + d0 + 4);
  float a0 = acc[0] + bb0.x, a1 = acc[1] + bb0.y;
  float a2 = acc[2] + bb0.z, a3 = acc[3] + bb0.w;
  float a4 = acc[4] + bb1.x, a5 = acc[5] + bb1.y;
  float a6 = acc[6] + bb1.z, a7 = acc[7] + bb1.w;

  float sum = ((a0 + a1) + (a2 + a3)) + ((a4 + a5) + (a6 + a7));
#pragma unroll
  for (int o = 8; o >= 1; o >>= 1) sum += __shfl_xor(sum, o, 16);
  float mu = sum * (1.0f / 128.0f);
  float e0 = a0 - mu, e1 = a1 - mu, e2 = a2 - mu, e3 = a3 - mu;
  float e4 = a4 - mu, e5 = a5 - mu, e6 = a6 - mu, e7 = a7 - mu;
  float vs = ((e0 * e0 + e1 * e1) + (e2 * e2 + e3 * e3)) +
             ((e4 * e4 + e5 * e5) + (e6 * e6 + e7 * e7));
#pragma unroll
  for (int o = 8; o >= 1; o >>= 1) vs += __shfl_xor(vs, o, 16);
  float inv = rsqrtf(vs * (1.0f / 128.0f) + EPS);

  float4 gg0 = *(const float4*)(g + d0);
  float4 gg1 = *(const float4*)(g + d0 + 4);
  float4 bl0 = *(const float4*)(bln + d0);
  float4 bl1 = *(const float4*)(bln + d0 + 4);
  out[0] = fmaxf(e0 * inv * gg0.x + bl0.x, 0.0f);
  out[1] = fmaxf(e1 * inv * gg0.y + bl0.y, 0.0f);
  out[2] = fmaxf(e2 * inv * gg0.z + bl0.z, 0.0f);
  out[3] = fmaxf(e3 * inv * gg0.w + bl0.w, 0.0f);
  out[4] = fmaxf(e4 * inv * gg1.x + bl1.x, 0.0f);
  out[5] = fmaxf(e5 * inv * gg1.y + bl1.y, 0.0f);
  out[6] = fmaxf(e6 * inv * gg1.z + bl1.z, 0.0f);
  out[7] = fmaxf(e7 * inv * gg1.w + bl1.w, 0.0f);
}

// P6a: pure gather1 + LN + ReLU -> y1 (fp16) in global. Rows via perm
// (degree-sorted) for wave/block load balance.
__global__ __launch_bounds__(256, 8) void k_gather1(
    const uint2* __restrict__ hb, const int4* __restrict__ meta,
    const u32* __restrict__ csr, const int* __restrict__ perm,
    const float* __restrict__ b, const float* __restrict__ g,
    const float* __restrict__ bln,
    u16* __restrict__ y1, int n) {
  const int tid = threadIdx.x;
  const int sl = tid & 15;
  const int pr = blockIdx.x * 16 + (tid >> 4);
  const int row = (pr < n) ? perm[pr] : n;
  float o[8];
  gather_ln_core(hb, meta, csr, b, g, bln, row, n, sl, o);
  if (pr >= n) return;
  uint4 pk;
  pk.x = ((u32)f2h(o[1]) << 16) | (u32)f2h(o[0]);
  pk.y = ((u32)f2h(o[3]) << 16) | (u32)f2h(o[2]);
  pk.z = ((u32)f2h(o[5]) << 16) | (u32)f2h(o[4]);
  pk.w = ((u32)f2h(o[7]) << 16) | (u32)f2h(o[6]);
  *(uint4*)(y1 + (size_t)row * D + sl * 8) = pk;
}

// P6b: standalone GEMM2: y1 (fp16) @ W2 -> B (h2, fp8).
__global__ __launch_bounds__(256) void k_gemm2(const u16* __restrict__ y1,
                                               const u16* __restrict__ Wt2,
                                               u8* __restrict__ outB, int n) {
  gemm_body<false>(y1, Wt2, outB, n, blockIdx.x);
}

// P7: gather2 + LN + ReLU + residual -> fp32 out. Rows via perm.
__global__ __launch_bounds__(256, 8) void k_gather2(
    const uint2* __restrict__ hb, const int4* __restrict__ meta,
    const u32* __restrict__ csr, const int* __restrict__ perm,
    const float* __restrict__ b, const float* __restrict__ g,
    const float* __restrict__ bln, const float* __restrict__ resid,
    float* __restrict__ outf, int n) {
  const int tid = threadIdx.x;
  const int sl = tid & 15;
  const int pr = blockIdx.x * 16 + (tid >> 4);
  const int row = (pr < n) ? perm[pr] : n;
  float o[8];
  gather_ln_core(hb, meta, csr, b, g, bln, row, n, sl, o);
  if (pr >= n) return;
  size_t base = (size_t)row * D + sl * 8;
  float4 r0 = *(const float4*)(resid + base);
  float4 r1 = *(const float4*)(resid + base + 4);
  *(float4*)(outf + base) =
      make_float4(o[0] + r0.x, o[1] + r0.y, o[2] + r0.z, o[3] + r0.w);
  *(float4*)(outf + base + 4) =
      make_float4(o[4] + r1.x, o[5] + r1.y, o[6] + r1.z, o[7] + r1.w);
}

// ---------------------------------------------------------------------------
extern "C" void kernel_launch(void* const* d_in, const int* in_sizes, int n_in,
                              void* d_out, int out_size, void* d_ws, size_t ws_size,
                              hipStream_t stream) {
  const float* x    = (const float*)d_in[0];
  const int*   ei   = (const int*)d_in[1];
  const float* W1   = (const float*)d_in[2];
  const float* b1   = (const float*)d_in[3];
  const float* g1   = (const float*)d_in[4];
  const float* bl1  = (const float*)d_in[5];
  const float* W2   = (const float*)d_in[6];
  const float* b2   = (const float*)d_in[7];
  const float* g2   = (const float*)d_in[8];
  const float* bl2  = (const float*)d_in[9];

  const int N = in_sizes[0] / D;
  const int E = in_sizes[1] / 2;
  const int* src = ei;
  const int* dst = ei + E;

  const int NB  = (N + BUCKW - 1) / BUCKW;  // coarse buckets (= NBK)
  const int M   = NB * KB;
  const int EPB = (E + KB - 1) / KB;        // edges per count/scatter block
  const int GB  = (N + 63) / 64;            // gemm blocks
  const int RB  = (N + 15) / 16;            // gather blocks (16 rows each)
  const int SB  = (M + 1023) / 1024;        // scan blocks

  size_t off = 0;
  auto walloc = [&](size_t bytes) {
    void* p = (char*)d_ws + off;
    off = (off + bytes + 255) & ~(size_t)255;
    return p;
  };
  int*   cnt    = (int*)walloc((size_t)M * 4);
  int*   bsum   = (int*)walloc((size_t)SB * 4);
  int*   bsv    = (int*)walloc((size_t)(NB + 1) * 4);
  int*   bc     = (int*)walloc((size_t)NB * 64 * 4);
  int*   pboff  = (int*)walloc((size_t)NB * 64 * 4);
  int*   bintot = (int*)walloc(64 * 4);
  int*   binbase= (int*)walloc(64 * 4);
  int*   perm   = (int*)walloc((size_t)N * 4);
  u32*   tmp    = (u32*)walloc((size_t)E * 4);
  u32*   csr    = (u32*)walloc((size_t)E * 4);
  int4*  meta   = (int4*)walloc((size_t)N * 16);
  float* dinv   = (float*)walloc((size_t)N * 4);
  u8*    A      = (u8*)walloc((size_t)N * D);        // h1 (fp8 e4m3)
  u8*    B      = (u8*)walloc((size_t)N * D);        // h2 (fp8 e4m3)
  u16*   Wt1    = (u16*)walloc((size_t)D * D * 2);
  u16*   Wt2    = (u16*)walloc((size_t)D * D * 2);
  u16*   y1     = (u16*)walloc((size_t)N * D * 2);   // LN1 out (fp16)
  float* O      = (float*)d_out;

  // P0: weight converts
  k_prep<<<(2 * D * D + 255) / 256, 256, 0, stream>>>(W1, W2, Wt1, Wt2);
  // ph1: coarse count || GEMM1 (x @ W1 -> A fp8)
  k_count_gemm1<<<KB + GB, 256, 0, stream>>>(dst, cnt, E, NB, EPB, x, Wt1, A, N);
  // ph2: parallel scan (reduce -> apply-with-inline-mid)
  k_scan_reduce<<<SB, 256, 0, stream>>>(cnt, M, bsum);
  k_scan_apply<<<SB, 256, 0, stream>>>(cnt, M, bsum, bsv, NB, E);
  // ph3: scatter into buckets
  k_scatter<<<KB, 256, 0, stream>>>(src, dst, cnt, tmp, E, NB, EPB);
  // ph4: per-bucket fine sort -> csr + meta + dinv + per-bucket degree hist
  k_bucket<<<NB, 256, 0, stream>>>(tmp, bsv, meta, dinv, csr, bc, N);
  // ph4b: per-bin scan over buckets
  k_permscan<<<64, 256, 0, stream>>>(bc, pboff, bintot, NB);
  // ph4c: bin base scan
  k_binscan<<<1, 64, 0, stream>>>(bintot, binbase);
  // ph5: pack weights + contention-free perm placement
  k_weights<<<NB, 512, 0, stream>>>(meta, dinv, csr, pboff, binbase, perm, N);
  // P6a: gather1 + LN + ReLU -> y1 (fp16)
  k_gather1<<<RB, 256, 0, stream>>>((const uint2*)A, meta, csr, perm,
                                    b1, g1, bl1, y1, N);
  // P6b: GEMM2 -> B (fp8)
  k_gemm2<<<GB, 256, 0, stream>>>(y1, Wt2, B, N);
  // P7: gather2 + LN + ReLU + residual -> O
  k_gather2<<<RB, 256, 0, stream>>>((const uint2*)B, meta, csr, perm,
                                    b2, g2, bl2, x, O, N);
}

// Round 9
// 195.444 us; speedup vs baseline: 1.8381x; 1.0181x over previous
//
#include <hip/hip_runtime.h>
#include <hip/hip_fp16.h>

#define D 128
#define EPS 1e-5f
#define KB 64          // coarse count/scatter blocks
#define NBSH 7         // bucket = dst >> 7
#define BUCKW 128      // dsts per bucket

typedef unsigned int u32;
typedef unsigned short u16;
typedef unsigned char u8;
typedef __attribute__((ext_vector_type(8))) _Float16 half8;  // mfma A/B frag
typedef __attribute__((ext_vector_type(4))) float f32x4;
typedef __attribute__((ext_vector_type(2))) float f32x2;

__device__ inline u16 f2h(float x) {
  _Float16 t = (_Float16)x;
  return __builtin_bit_cast(u16, t);
}
__device__ inline u8 f2fp8(float x) {
  return (u8)(__builtin_amdgcn_cvt_pk_fp8_f32(x, x, 0, false) & 0xff);
}

// ---------------------------------------------------------------------------
// P0: convert W1,W2 fp32[k][c] -> fp16 Wt[c][k].
__global__ __launch_bounds__(256) void k_prep(const float* __restrict__ W1,
                                              const float* __restrict__ W2,
                                              u16* __restrict__ Wt1,
                                              u16* __restrict__ Wt2) {
  int i = blockIdx.x * 256 + threadIdx.x;
  if (i < 2 * D * D) {
    const float* W = (i < D * D) ? W1 : W2;
    u16* Wt = (i < D * D) ? Wt1 : Wt2;
    int ii = i & (D * D - 1);
    int k = ii >> 7, c = ii & 127;
    Wt[c * D + k] = f2h(W[ii]);
  }
}

// ---------------------------------------------------------------------------
// LDS-free MFMA GEMM body; OUTPUT IS FP8 (e4m3). A-frag from global
// (contiguous 16B in k); B from Wt[c][k] (L2-hot); D: col=ct*16+m, row=q*4+reg.
template <bool F32IN>
__device__ __forceinline__ void gemm_body(const void* __restrict__ in_,
                                          const u16* __restrict__ Wt,
                                          u8* __restrict__ out, int nrows,
                                          int blk) {
  const int tid = threadIdx.x;
  const int lane = tid & 63, wv = tid >> 6;
  const int m = lane & 15, q = lane >> 4;
  const int r0 = blk * 64 + wv * 16;
  const int rowa = min(r0 + m, nrows - 1);

  f32x4 acc[8];
#pragma unroll
  for (int ct = 0; ct < 8; ct++) acc[ct] = (f32x4)(0.0f);

#pragma unroll
  for (int kk = 0; kk < 4; kk++) {
    const int kbase = kk * 32 + q * 8;
    half8 a;
    if (F32IN) {
      const float* in = (const float*)in_;
      float4 v0 = *(const float4*)(in + (size_t)rowa * D + kbase);
      float4 v1 = *(const float4*)(in + (size_t)rowa * D + kbase + 4);
      a[0] = (_Float16)v0.x; a[1] = (_Float16)v0.y;
      a[2] = (_Float16)v0.z; a[3] = (_Float16)v0.w;
      a[4] = (_Float16)v1.x; a[5] = (_Float16)v1.y;
      a[6] = (_Float16)v1.z; a[7] = (_Float16)v1.w;
    } else {
      const u16* in = (const u16*)in_;
      a = *(const half8*)(in + (size_t)rowa * D + kbase);
    }
#pragma unroll
    for (int ct = 0; ct < 8; ct++) {
      half8 b = *(const half8*)(Wt + (ct * 16 + m) * D + kbase);
      acc[ct] = __builtin_amdgcn_mfma_f32_16x16x32_f16(a, b, acc[ct], 0, 0, 0);
    }
  }

#pragma unroll
  for (int ct = 0; ct < 8; ct++) {
#pragma unroll
    for (int rg = 0; rg < 4; rg++) {
      int rr = r0 + q * 4 + rg;
      if (rr < nrows) out[(size_t)rr * D + ct * 16 + m] = f2fp8(acc[ct][rg]);
    }
  }
}

// ph1: coarse-bucket count, 8-deep batched (blocks [0,KB)) || GEMM1.
__global__ __launch_bounds__(256) void k_count_gemm1(
    const int* __restrict__ dst, int* __restrict__ cnt, int E, int NB, int EPB,
    const float* __restrict__ x, const u16* __restrict__ Wt1,
    u8* __restrict__ A, int nrows) {
  if (blockIdx.x < (u32)KB) {
    __shared__ int hist[512];
    const int k = blockIdx.x, tid = threadIdx.x;
    for (int i = tid; i < NB; i += 256) hist[i] = 0;
    __syncthreads();
    const int e0 = k * EPB, e1 = min(E, e0 + EPB);
    for (int base = e0 + tid; base < e1; base += 2048) {
      int dd[8];
#pragma unroll
      for (int i = 0; i < 8; i++) {
        int e = base + i * 256;
        dd[i] = (e < e1) ? dst[e] : -1;
      }
#pragma unroll
      for (int i = 0; i < 8; i++)
        if (dd[i] >= 0) atomicAdd(&hist[dd[i] >> NBSH], 1);
    }
    __syncthreads();
    for (int b = tid; b < NB; b += 256) cnt[b * KB + k] = hist[b];
  } else {
    gemm_body<true>(x, Wt1, A, nrows, blockIdx.x - KB);
  }
}

// ph2a: per-block (1024 elem) reduce -> bsum.
__global__ __launch_bounds__(256) void k_scan_reduce(
    const int* __restrict__ cnt, int M, int* __restrict__ bsum) {
  const int b = blockIdx.x, t = threadIdx.x;
  const int lane = t & 63, w = t >> 6;
  int idx = b * 1024 + t * 4;
  int4 v = make_int4(0, 0, 0, 0);
  if (idx + 3 < M) {
    v = *(const int4*)(cnt + idx);
  } else {
    if (idx + 0 < M) v.x = cnt[idx + 0];
    if (idx + 1 < M) v.y = cnt[idx + 1];
    if (idx + 2 < M) v.z = cnt[idx + 2];
  }
  int s = v.x + v.y + v.z + v.w;
#pragma unroll
  for (int o = 1; o < 64; o <<= 1) s += __shfl_xor(s, o, 64);
  __shared__ int ws[4];
  if (lane == 0) ws[w] = s;
  __syncthreads();
  if (t == 0) bsum[b] = ws[0] + ws[1] + ws[2] + ws[3];
}

// ph2b: per-block local scan; block offset = sum of bsum[0..b-1] (inline mid).
__global__ __launch_bounds__(256) void k_scan_apply(
    int* __restrict__ cnt, int M, const int* __restrict__ bsum,
    int* __restrict__ bsv, int NB, int E) {
  const int b = blockIdx.x, t = threadIdx.x;
  const int lane = t & 63, w = t >> 6;
  if (b == 0 && t == 0) bsv[NB] = E;
  int idx = b * 1024 + t * 4;
  int4 v = make_int4(0, 0, 0, 0);
  if (idx + 3 < M) {
    v = *(const int4*)(cnt + idx);
  } else {
    if (idx + 0 < M) v.x = cnt[idx + 0];
    if (idx + 1 < M) v.y = cnt[idx + 1];
    if (idx + 2 < M) v.z = cnt[idx + 2];
  }
  int s = v.x + v.y + v.z + v.w;
  int incl = s;
#pragma unroll
  for (int o = 1; o < 64; o <<= 1) {
    int u = __shfl_up(incl, o, 64);
    if (lane >= o) incl += u;
  }
  __shared__ int ws[4];
  __shared__ int sboff;
  if (lane == 63) ws[w] = incl;
  if (t < 64) {
    int partial = 0;
    for (int j = t; j < b; j += 64) partial += bsum[j];
#pragma unroll
    for (int o = 32; o >= 1; o >>= 1) partial += __shfl_xor(partial, o, 64);
    if (t == 0) sboff = partial;
  }
  __syncthreads();
  int wbase = 0;
#pragma unroll
  for (int j = 0; j < 4; j++)
    if (j < w) wbase += ws[j];
  int base = sboff + wbase + incl - s;  // exclusive prefix for idx
  int e0 = base, e1 = e0 + v.x, e2 = e1 + v.y, e3 = e2 + v.z;
  // idx is a multiple of 4; only idx itself can be a multiple of KB=64.
  if (idx < M) {
    cnt[idx] = e0;
    if ((idx & (KB - 1)) == 0) bsv[idx >> 6] = e0;
  }
  if (idx + 1 < M) cnt[idx + 1] = e1;
  if (idx + 2 < M) cnt[idx + 2] = e2;
  if (idx + 3 < M) cnt[idx + 3] = e3;
}

// ph3: scatter edges into bucket-grouped tmp via LDS cursors, 8-deep batched.
__global__ __launch_bounds__(256) void k_scatter(
    const int* __restrict__ src, const int* __restrict__ dst,
    const int* __restrict__ cnt, u32* __restrict__ tmp, int E, int NB,
    int EPB) {
  __shared__ int off[512];
  const int k = blockIdx.x, tid = threadIdx.x;
  for (int b = tid; b < NB; b += 256) off[b] = cnt[b * KB + k];
  __syncthreads();
  const int e0 = k * EPB, e1 = min(E, e0 + EPB);
  for (int base = e0 + tid; base < e1; base += 2048) {
    int dd[8], ss[8];
#pragma unroll
    for (int i = 0; i < 8; i++) {
      int e = base + i * 256;
      dd[i] = (e < e1) ? dst[e] : -1;
      ss[i] = (e < e1) ? src[e] : 0;
    }
#pragma unroll
    for (int i = 0; i < 8; i++) {
      if (dd[i] >= 0) {
        int p = atomicAdd(&off[dd[i] >> NBSH], 1);
        tmp[p] = (u32)ss[i] | ((u32)(dd[i] & (BUCKW - 1)) << 16);
      }
    }
  }
}

// ph4: one block per bucket: fine 128-bin LDS hist + scan -> deg/dinv/meta,
// then dst-sorted csr with per-row SRC-SLAB PARTITION: entries with
// src < SLAB placed ascending from row start (cursor lo), src >= SLAB
// descending from row end (cursor hi). Split count -> meta.w.
__global__ __launch_bounds__(256) void k_bucket(
    const u32* __restrict__ tmp, const int* __restrict__ bsv,
    int4* __restrict__ meta, float* __restrict__ dinv,
    u32* __restrict__ csr, int N, int SLAB) {
  __shared__ int hist[BUCKW];
  __shared__ int sc[BUCKW];
  __shared__ int curlo[BUCKW];
  __shared__ int curhi[BUCKW];
  const int b = blockIdx.x, tid = threadIdx.x;
  const int s0 = bsv[b], s1 = bsv[b + 1];
  if (tid < BUCKW) hist[tid] = 0;
  __syncthreads();
  for (int base = s0 + tid; base < s1; base += 1024) {
    int tt[4];
#pragma unroll
    for (int i = 0; i < 4; i++) {
      int idx = base + i * 256;
      tt[i] = (idx < s1) ? (int)tmp[idx] : -1;
    }
#pragma unroll
    for (int i = 0; i < 4; i++)
      if (tt[i] >= 0) atomicAdd(&hist[(tt[i] >> 16) & (BUCKW - 1)], 1);
  }
  __syncthreads();
  if (tid < BUCKW) sc[tid] = hist[tid];
  __syncthreads();
#pragma unroll
  for (int o = 1; o < BUCKW; o <<= 1) {
    int t = 0;
    if (tid < BUCKW && tid >= o) t = sc[tid - o];
    __syncthreads();
    if (tid < BUCKW) sc[tid] += t;
    __syncthreads();
  }
  if (tid < BUCKW) {
    int dg = hist[tid];
    int excl = sc[tid] - dg;
    curlo[tid] = excl;
    curhi[tid] = excl + dg - 1;
    int d = (b << NBSH) + tid;
    if (d < N) {
      float dv = rsqrtf((float)dg + 1.0f);
      meta[d] = make_int4(s0 + excl, dg, __builtin_bit_cast(int, dv), 0);
      dinv[d] = dv;
    }
  }
  __syncthreads();
  for (int base = s0 + tid; base < s1; base += 1024) {
    int tt[4];
#pragma unroll
    for (int i = 0; i < 4; i++) {
      int idx = base + i * 256;
      tt[i] = (idx < s1) ? (int)tmp[idx] : -1;
    }
#pragma unroll
    for (int i = 0; i < 4; i++) {
      if (tt[i] >= 0) {
        int dl = (tt[i] >> 16) & (BUCKW - 1);
        int sr = (int)((u32)tt[i] & 0xffffu);
        int r = (sr < SLAB) ? atomicAdd(&curlo[dl], 1)
                            : atomicSub(&curhi[dl], 1);
        csr[s0 + r] = (u32)sr;
      }
    }
  }
  __syncthreads();
  if (tid < BUCKW) {
    int d = (b << NBSH) + tid;
    if (d < N) {
      int excl = sc[tid] - hist[tid];
      ((int*)meta)[d * 4 + 3] = curlo[tid] - excl;  // slab0 count
    }
  }
}

// ph5: pack weights: csr entry src -> src | fp16(dinv[s]*dinv[d])<<16.
__global__ __launch_bounds__(256) void k_weights(
    const int4* __restrict__ meta, const float* __restrict__ dinv,
    u32* __restrict__ csr, int N) {
  int gid = blockIdx.x * 256 + threadIdx.x;
  int r = gid >> 2, j0 = gid & 3;
  if (r >= N) return;
  int4 mt = meta[r];
  float dv = __builtin_bit_cast(float, mt.z);
  for (int j = j0; j < mt.y; j += 4) {
    u32 s = csr[mt.x + j];
    float w = dinv[s] * dv;
    csr[mt.x + j] = s | ((u32)f2h(w) << 16);
  }
}

// ---------------------------------------------------------------------------
// Gather+LN core — FP8 h rows (128 B), fp32 accumulation.
// Row owned by 16 lanes, uint2 (8 fp8) per lane.
// TWO PHASES by src slab (csr pre-partitioned): chip-wide, waves process
// slab0 then slab1, so the active 3.2MB source slab stays L2-resident.
#define ACC_EDGE(vv, ee)                                                     \
  {                                                                          \
    float ww = (float)__builtin_bit_cast(_Float16, (u16)((ee) >> 16));       \
    f32x2 p_;                                                                \
    p_ = __builtin_amdgcn_cvt_pk_f32_fp8(vv.x, false);                       \
    acc[0] = fmaf(p_[0], ww, acc[0]); acc[1] = fmaf(p_[1], ww, acc[1]);      \
    p_ = __builtin_amdgcn_cvt_pk_f32_fp8(vv.x, true);                        \
    acc[2] = fmaf(p_[0], ww, acc[2]); acc[3] = fmaf(p_[1], ww, acc[3]);      \
    p_ = __builtin_amdgcn_cvt_pk_f32_fp8(vv.y, false);                       \
    acc[4] = fmaf(p_[0], ww, acc[4]); acc[5] = fmaf(p_[1], ww, acc[5]);      \
    p_ = __builtin_amdgcn_cvt_pk_f32_fp8(vv.y, true);                        \
    acc[6] = fmaf(p_[0], ww, acc[6]); acc[7] = fmaf(p_[1], ww, acc[7]);      \
  }

__device__ __forceinline__ void gather_ln_core(
    const uint2* __restrict__ hb, const int4* __restrict__ meta,
    const u32* __restrict__ csr, const float* __restrict__ b,
    const float* __restrict__ g, const float* __restrict__ bln,
    int row, int n, int sl, float out[8]) {
  const bool valid = row < n;
  const int rc = valid ? row : 0;
  int4 mt = meta[rc];
  int beg = mt.x;
  int cnt = valid ? mt.y : 0;
  int c0 = valid ? mt.w : 0;        // slab0 count
  float dv = __builtin_bit_cast(float, mt.z);
  float sn = dv * dv;

  float acc[8];
  {
    uint2 su = hb[(size_t)rc * 16 + sl];
    f32x2 p0 = __builtin_amdgcn_cvt_pk_f32_fp8(su.x, false);
    f32x2 p1 = __builtin_amdgcn_cvt_pk_f32_fp8(su.x, true);
    f32x2 p2 = __builtin_amdgcn_cvt_pk_f32_fp8(su.y, false);
    f32x2 p3 = __builtin_amdgcn_cvt_pk_f32_fp8(su.y, true);
    acc[0] = p0[0] * sn; acc[1] = p0[1] * sn;
    acc[2] = p1[0] * sn; acc[3] = p1[1] * sn;
    acc[4] = p2[0] * sn; acc[5] = p2[1] * sn;
    acc[6] = p3[0] * sn; acc[7] = p3[1] * sn;
  }

  // ---- phase 0: slab0 edges [beg, beg+c0) ----
  int cm0 = max(c0, __shfl_xor(c0, 16, 64));
  cm0 = max(cm0, __shfl_xor(cm0, 32, 64));
  for (int j0 = 0; j0 < cm0; j0 += 8) {
    u32 e[8];
#pragma unroll
    for (int jj = 0; jj < 8; jj++) {
      int j = j0 + jj;
      e[jj] = (j < c0) ? csr[beg + j] : 0u;   // uniform per 16-lane group
    }
    uint2 v[8];
#pragma unroll
    for (int jj = 0; jj < 8; jj++)
      v[jj] = hb[(size_t)(e[jj] & 0xffffu) * 16 + sl];
#pragma unroll
    for (int jj = 0; jj < 8; jj++) ACC_EDGE(v[jj], e[jj]);
  }

  // ---- phase 1: slab1 edges [beg+c0, beg+cnt) ----
  int c1 = cnt - c0;
  int cm1 = max(c1, __shfl_xor(c1, 16, 64));
  cm1 = max(cm1, __shfl_xor(cm1, 32, 64));
  const int b1 = beg + c0;
  for (int j0 = 0; j0 < cm1; j0 += 8) {
    u32 e[8];
#pragma unroll
    for (int jj = 0; jj < 8; jj++) {
      int j = j0 + jj;
      e[jj] = (j < c1) ? csr[b1 + j] : 0u;
    }
    uint2 v[8];
#pragma unroll
    for (int jj = 0; jj < 8; jj++)
      v[jj] = hb[(size_t)(e[jj] & 0xffffu) * 16 + sl];
#pragma unroll
    for (int jj = 0; jj < 8; jj++) ACC_EDGE(v[jj], e[jj]);
  }

  // ---- LayerNorm over 128 cols, 8 per lane across 16 lanes ----
  int d0 = sl * 8;
  float4 bb0 = *(const float4*)(b + d0);
  float4 bb1 = *(const float4*)(b + d0 + 4);
  float a0 = acc[0] + bb0.x, a1 = acc[1] + bb0.y;
  float a2 = acc[2] + bb0.z, a3 = acc[3] + bb0.w;
  float a4 = acc[4] + bb1.x, a5 = acc[5] + bb1.y;
  float a6 = acc[6] + bb1.z, a7 = acc[7] + bb1.w;

  float sum = ((a0 + a1) + (a2 + a3)) + ((a4 + a5) + (a6 + a7));
#pragma unroll
  for (int o = 8; o >= 1; o >>= 1) sum += __shfl_xor(sum, o, 16);
  float mu = sum * (1.0f / 128.0f);
  float e0 = a0 - mu, e1 = a1 - mu, e2 = a2 - mu, e3 = a3 - mu;
  float e4 = a4 - mu, e5 = a5 - mu, e6 = a6 - mu, e7 = a7 - mu;
  float vs = ((e0 * e0 + e1 * e1) + (e2 * e2 + e3 * e3)) +
             ((e4 * e4 + e5 * e5) + (e6 * e6 + e7 * e7));
#pragma unroll
  for (int o = 8; o >= 1; o >>= 1) vs += __shfl_xor(vs, o, 16);
  float inv = rsqrtf(vs * (1.0f / 128.0f) + EPS);

  float4 gg0 = *(const float4*)(g + d0);
  float4 gg1 = *(const float4*)(g + d0 + 4);
  float4 bl0 = *(const float4*)(bln + d0);
  float4 bl1 = *(const float4*)(bln + d0 + 4);
  out[0] = fmaxf(e0 * inv * gg0.x + bl0.x, 0.0f);
  out[1] = fmaxf(e1 * inv * gg0.y + bl0.y, 0.0f);
  out[2] = fmaxf(e2 * inv * gg0.z + bl0.z, 0.0f);
  out[3] = fmaxf(e3 * inv * gg0.w + bl0.w, 0.0f);
  out[4] = fmaxf(e4 * inv * gg1.x + bl1.x, 0.0f);
  out[5] = fmaxf(e5 * inv * gg1.y + bl1.y, 0.0f);
  out[6] = fmaxf(e6 * inv * gg1.z + bl1.z, 0.0f);
  out[7] = fmaxf(e7 * inv * gg1.w + bl1.w, 0.0f);
}

// P6a: pure gather1 + LN + ReLU -> y1 (fp16) in global. No LDS, no barrier,
// 64-VGPR target for 8 waves/SIMD residency (latency-bound random gather).
__global__ __launch_bounds__(256, 8) void k_gather1(
    const uint2* __restrict__ hb, const int4* __restrict__ meta,
    const u32* __restrict__ csr,
    const float* __restrict__ b, const float* __restrict__ g,
    const float* __restrict__ bln,
    u16* __restrict__ y1, int n) {
  const int tid = threadIdx.x;
  const int sl = tid & 15;
  const int row = blockIdx.x * 16 + (tid >> 4);
  float o[8];
  gather_ln_core(hb, meta, csr, b, g, bln, row, n, sl, o);
  if (row >= n) return;
  uint4 pk;
  pk.x = ((u32)f2h(o[1]) << 16) | (u32)f2h(o[0]);
  pk.y = ((u32)f2h(o[3]) << 16) | (u32)f2h(o[2]);
  pk.z = ((u32)f2h(o[5]) << 16) | (u32)f2h(o[4]);
  pk.w = ((u32)f2h(o[7]) << 16) | (u32)f2h(o[6]);
  *(uint4*)(y1 + (size_t)row * D + sl * 8) = pk;
}

// P6b: standalone GEMM2: y1 (fp16) @ W2 -> B (h2, fp8).
__global__ __launch_bounds__(256) void k_gemm2(const u16* __restrict__ y1,
                                               const u16* __restrict__ Wt2,
                                               u8* __restrict__ outB, int n) {
  gemm_body<false>(y1, Wt2, outB, n, blockIdx.x);
}

// P7: gather2 + LN + ReLU + residual -> fp32 out. Residual read and final
// store are non-temporal (pure streaming, ext-vector type) to keep the
// active B slab L2-resident.
__global__ __launch_bounds__(256, 8) void k_gather2(
    const uint2* __restrict__ hb, const int4* __restrict__ meta,
    const u32* __restrict__ csr,
    const float* __restrict__ b, const float* __restrict__ g,
    const float* __restrict__ bln, const float* __restrict__ resid,
    float* __restrict__ outf, int n) {
  const int tid = threadIdx.x;
  const int sl = tid & 15;
  const int row = blockIdx.x * 16 + (tid >> 4);
  float o[8];
  gather_ln_core(hb, meta, csr, b, g, bln, row, n, sl, o);
  if (row >= n) return;
  size_t base = (size_t)row * D + sl * 8;
  f32x4 r0 = __builtin_nontemporal_load((const f32x4*)(resid + base));
  f32x4 r1 = __builtin_nontemporal_load((const f32x4*)(resid + base + 4));
  f32x4 w0, w1;
  w0[0] = o[0] + r0[0]; w0[1] = o[1] + r0[1];
  w0[2] = o[2] + r0[2]; w0[3] = o[3] + r0[3];
  w1[0] = o[4] + r1[0]; w1[1] = o[5] + r1[1];
  w1[2] = o[6] + r1[2]; w1[3] = o[7] + r1[3];
  __builtin_nontemporal_store(w0, (f32x4*)(outf + base));
  __builtin_nontemporal_store(w1, (f32x4*)(outf + base + 4));
}

// ---------------------------------------------------------------------------
extern "C" void kernel_launch(void* const* d_in, const int* in_sizes, int n_in,
                              void* d_out, int out_size, void* d_ws, size_t ws_size,
                              hipStream_t stream) {
  const float* x    = (const float*)d_in[0];
  const int*   ei   = (const int*)d_in[1];
  const float* W1   = (const float*)d_in[2];
  const float* b1   = (const float*)d_in[3];
  const float* g1   = (const float*)d_in[4];
  const float* bl1  = (const float*)d_in[5];
  const float* W2   = (const float*)d_in[6];
  const float* b2   = (const float*)d_in[7];
  const float* g2   = (const float*)d_in[8];
  const float* bl2  = (const float*)d_in[9];

  const int N = in_sizes[0] / D;
  const int E = in_sizes[1] / 2;
  const int* src = ei;
  const int* dst = ei + E;

  const int NB  = (N + BUCKW - 1) / BUCKW;  // coarse buckets
  const int M   = NB * KB;
  const int EPB = (E + KB - 1) / KB;        // edges per count/scatter block
  const int GB  = (N + 63) / 64;            // gemm blocks
  const int RB  = (N + 15) / 16;            // gather blocks (16 rows each)
  const int SB  = (M + 1023) / 1024;        // scan blocks
  const int SLAB = (N + 1) / 2;             // src slab boundary (~3.2MB of rows)

  size_t off = 0;
  auto walloc = [&](size_t bytes) {
    void* p = (char*)d_ws + off;
    off = (off + bytes + 255) & ~(size_t)255;
    return p;
  };
  int*   cnt   = (int*)walloc((size_t)M * 4);
  int*   bsum  = (int*)walloc((size_t)SB * 4);
  int*   bsv   = (int*)walloc((size_t)(NB + 1) * 4);
  u32*   tmp   = (u32*)walloc((size_t)E * 4);
  u32*   csr   = (u32*)walloc((size_t)E * 4);
  int4*  meta  = (int4*)walloc((size_t)N * 16);
  float* dinv  = (float*)walloc((size_t)N * 4);
  u8*    A     = (u8*)walloc((size_t)N * D);        // h1 (fp8 e4m3)
  u8*    B     = (u8*)walloc((size_t)N * D);        // h2 (fp8 e4m3)
  u16*   Wt1   = (u16*)walloc((size_t)D * D * 2);
  u16*   Wt2   = (u16*)walloc((size_t)D * D * 2);
  u16*   y1    = (u16*)walloc((size_t)N * D * 2);   // LN1 out (fp16)
  float* O     = (float*)d_out;

  // P0: weight converts
  k_prep<<<(2 * D * D + 255) / 256, 256, 0, stream>>>(W1, W2, Wt1, Wt2);
  // ph1: coarse count || GEMM1 (x @ W1 -> A fp8)
  k_count_gemm1<<<KB + GB, 256, 0, stream>>>(dst, cnt, E, NB, EPB, x, Wt1, A, N);
  // ph2: parallel scan (reduce -> apply-with-inline-mid)
  k_scan_reduce<<<SB, 256, 0, stream>>>(cnt, M, bsum);
  k_scan_apply<<<SB, 256, 0, stream>>>(cnt, M, bsum, bsv, NB, E);
  // ph3: scatter into buckets
  k_scatter<<<KB, 256, 0, stream>>>(src, dst, cnt, tmp, E, NB, EPB);
  // ph4: per-bucket fine sort -> csr (slab-partitioned) + meta + dinv
  k_bucket<<<NB, 256, 0, stream>>>(tmp, bsv, meta, dinv, csr, N, SLAB);
  // ph5: pack weights
  k_weights<<<(N * 4 + 255) / 256, 256, 0, stream>>>(meta, dinv, csr, N);
  // P6a: gather1 + LN + ReLU -> y1 (fp16)
  k_gather1<<<RB, 256, 0, stream>>>((const uint2*)A, meta, csr, b1, g1, bl1,
                                    y1, N);
  // P6b: GEMM2 -> B (fp8)
  k_gemm2<<<GB, 256, 0, stream>>>(y1, Wt2, B, N);
  // P7: gather2 + LN + ReLU + residual -> O
  k_gather2<<<RB, 256, 0, stream>>>((const uint2*)B, meta, csr,
                                    b2, g2, bl2, x, O, N);
}

// Round 10
// 191.324 us; speedup vs baseline: 1.8777x; 1.0215x over previous
//
#include <hip/hip_runtime.h>
#include <hip/hip_fp16.h>

#define D 128
#define EPS 1e-5f
#define KB 64          // coarse count/scatter blocks
#define NBSH 7         // bucket = dst >> 7
#define BUCKW 128      // dsts per bucket

typedef unsigned int u32;
typedef unsigned short u16;
typedef unsigned char u8;
typedef __attribute__((ext_vector_type(8))) _Float16 half8;  // mfma A/B frag
typedef __attribute__((ext_vector_type(4))) float f32x4;
typedef __attribute__((ext_vector_type(2))) float f32x2;

__device__ inline u16 f2h(float x) {
  _Float16 t = (_Float16)x;
  return __builtin_bit_cast(u16, t);
}
__device__ inline u8 f2fp8(float x) {
  return (u8)(__builtin_amdgcn_cvt_pk_fp8_f32(x, x, 0, false) & 0xff);
}

// ---------------------------------------------------------------------------
// P0: convert W1,W2 fp32[k][c] -> fp16 Wt[c][k].
__global__ __launch_bounds__(256) void k_prep(const float* __restrict__ W1,
                                              const float* __restrict__ W2,
                                              u16* __restrict__ Wt1,
                                              u16* __restrict__ Wt2) {
  int i = blockIdx.x * 256 + threadIdx.x;
  if (i < 2 * D * D) {
    const float* W = (i < D * D) ? W1 : W2;
    u16* Wt = (i < D * D) ? Wt1 : Wt2;
    int ii = i & (D * D - 1);
    int k = ii >> 7, c = ii & 127;
    Wt[c * D + k] = f2h(W[ii]);
  }
}

// ---------------------------------------------------------------------------
// LDS-free MFMA GEMM body; OUTPUT IS FP8 (e4m3). A-frag from global
// (contiguous 16B in k); B from Wt[c][k] (L2-hot); D: col=ct*16+m, row=q*4+reg.
template <bool F32IN>
__device__ __forceinline__ void gemm_body(const void* __restrict__ in_,
                                          const u16* __restrict__ Wt,
                                          u8* __restrict__ out, int nrows,
                                          int blk) {
  const int tid = threadIdx.x;
  const int lane = tid & 63, wv = tid >> 6;
  const int m = lane & 15, q = lane >> 4;
  const int r0 = blk * 64 + wv * 16;
  const int rowa = min(r0 + m, nrows - 1);

  f32x4 acc[8];
#pragma unroll
  for (int ct = 0; ct < 8; ct++) acc[ct] = (f32x4)(0.0f);

#pragma unroll
  for (int kk = 0; kk < 4; kk++) {
    const int kbase = kk * 32 + q * 8;
    half8 a;
    if (F32IN) {
      const float* in = (const float*)in_;
      float4 v0 = *(const float4*)(in + (size_t)rowa * D + kbase);
      float4 v1 = *(const float4*)(in + (size_t)rowa * D + kbase + 4);
      a[0] = (_Float16)v0.x; a[1] = (_Float16)v0.y;
      a[2] = (_Float16)v0.z; a[3] = (_Float16)v0.w;
      a[4] = (_Float16)v1.x; a[5] = (_Float16)v1.y;
      a[6] = (_Float16)v1.z; a[7] = (_Float16)v1.w;
    } else {
      const u16* in = (const u16*)in_;
      a = *(const half8*)(in + (size_t)rowa * D + kbase);
    }
#pragma unroll
    for (int ct = 0; ct < 8; ct++) {
      half8 b = *(const half8*)(Wt + (ct * 16 + m) * D + kbase);
      acc[ct] = __builtin_amdgcn_mfma_f32_16x16x32_f16(a, b, acc[ct], 0, 0, 0);
    }
  }

#pragma unroll
  for (int ct = 0; ct < 8; ct++) {
#pragma unroll
    for (int rg = 0; rg < 4; rg++) {
      int rr = r0 + q * 4 + rg;
      if (rr < nrows) out[(size_t)rr * D + ct * 16 + m] = f2fp8(acc[ct][rg]);
    }
  }
}

// ph1: coarse-bucket count, 8-deep batched (blocks [0,KB)) || GEMM1.
__global__ __launch_bounds__(256) void k_count_gemm1(
    const int* __restrict__ dst, int* __restrict__ cnt, int E, int NB, int EPB,
    const float* __restrict__ x, const u16* __restrict__ Wt1,
    u8* __restrict__ A, int nrows) {
  if (blockIdx.x < (u32)KB) {
    __shared__ int hist[512];
    const int k = blockIdx.x, tid = threadIdx.x;
    for (int i = tid; i < NB; i += 256) hist[i] = 0;
    __syncthreads();
    const int e0 = k * EPB, e1 = min(E, e0 + EPB);
    for (int base = e0 + tid; base < e1; base += 2048) {
      int dd[8];
#pragma unroll
      for (int i = 0; i < 8; i++) {
        int e = base + i * 256;
        dd[i] = (e < e1) ? dst[e] : -1;
      }
#pragma unroll
      for (int i = 0; i < 8; i++)
        if (dd[i] >= 0) atomicAdd(&hist[dd[i] >> NBSH], 1);
    }
    __syncthreads();
    for (int b = tid; b < NB; b += 256) cnt[b * KB + k] = hist[b];
  } else {
    gemm_body<true>(x, Wt1, A, nrows, blockIdx.x - KB);
  }
}

// ph2a: per-block (1024 elem) reduce -> bsum.
__global__ __launch_bounds__(256) void k_scan_reduce(
    const int* __restrict__ cnt, int M, int* __restrict__ bsum) {
  const int b = blockIdx.x, t = threadIdx.x;
  const int lane = t & 63, w = t >> 6;
  int idx = b * 1024 + t * 4;
  int4 v = make_int4(0, 0, 0, 0);
  if (idx + 3 < M) {
    v = *(const int4*)(cnt + idx);
  } else {
    if (idx + 0 < M) v.x = cnt[idx + 0];
    if (idx + 1 < M) v.y = cnt[idx + 1];
    if (idx + 2 < M) v.z = cnt[idx + 2];
  }
  int s = v.x + v.y + v.z + v.w;
#pragma unroll
  for (int o = 1; o < 64; o <<= 1) s += __shfl_xor(s, o, 64);
  __shared__ int ws[4];
  if (lane == 0) ws[w] = s;
  __syncthreads();
  if (t == 0) bsum[b] = ws[0] + ws[1] + ws[2] + ws[3];
}

// ph2b: per-block local scan; block offset = sum of bsum[0..b-1] (inline mid).
__global__ __launch_bounds__(256) void k_scan_apply(
    int* __restrict__ cnt, int M, const int* __restrict__ bsum,
    int* __restrict__ bsv, int NB, int E) {
  const int b = blockIdx.x, t = threadIdx.x;
  const int lane = t & 63, w = t >> 6;
  if (b == 0 && t == 0) bsv[NB] = E;
  int idx = b * 1024 + t * 4;
  int4 v = make_int4(0, 0, 0, 0);
  if (idx + 3 < M) {
    v = *(const int4*)(cnt + idx);
  } else {
    if (idx + 0 < M) v.x = cnt[idx + 0];
    if (idx + 1 < M) v.y = cnt[idx + 1];
    if (idx + 2 < M) v.z = cnt[idx + 2];
  }
  int s = v.x + v.y + v.z + v.w;
  int incl = s;
#pragma unroll
  for (int o = 1; o < 64; o <<= 1) {
    int u = __shfl_up(incl, o, 64);
    if (lane >= o) incl += u;
  }
  __shared__ int ws[4];
  __shared__ int sboff;
  if (lane == 63) ws[w] = incl;
  if (t < 64) {
    int partial = 0;
    for (int j = t; j < b; j += 64) partial += bsum[j];
#pragma unroll
    for (int o = 32; o >= 1; o >>= 1) partial += __shfl_xor(partial, o, 64);
    if (t == 0) sboff = partial;
  }
  __syncthreads();
  int wbase = 0;
#pragma unroll
  for (int j = 0; j < 4; j++)
    if (j < w) wbase += ws[j];
  int base = sboff + wbase + incl - s;  // exclusive prefix for idx
  int e0 = base, e1 = e0 + v.x, e2 = e1 + v.y, e3 = e2 + v.z;
  // idx is a multiple of 4; only idx itself can be a multiple of KB=64.
  if (idx < M) {
    cnt[idx] = e0;
    if ((idx & (KB - 1)) == 0) bsv[idx >> 6] = e0;
  }
  if (idx + 1 < M) cnt[idx + 1] = e1;
  if (idx + 2 < M) cnt[idx + 2] = e2;
  if (idx + 3 < M) cnt[idx + 3] = e3;
}

// ph3: scatter edges into bucket-grouped tmp via LDS cursors, 8-deep batched.
__global__ __launch_bounds__(256) void k_scatter(
    const int* __restrict__ src, const int* __restrict__ dst,
    const int* __restrict__ cnt, u32* __restrict__ tmp, int E, int NB,
    int EPB) {
  __shared__ int off[512];
  const int k = blockIdx.x, tid = threadIdx.x;
  for (int b = tid; b < NB; b += 256) off[b] = cnt[b * KB + k];
  __syncthreads();
  const int e0 = k * EPB, e1 = min(E, e0 + EPB);
  for (int base = e0 + tid; base < e1; base += 2048) {
    int dd[8], ss[8];
#pragma unroll
    for (int i = 0; i < 8; i++) {
      int e = base + i * 256;
      dd[i] = (e < e1) ? dst[e] : -1;
      ss[i] = (e < e1) ? src[e] : 0;
    }
#pragma unroll
    for (int i = 0; i < 8; i++) {
      if (dd[i] >= 0) {
        int p = atomicAdd(&off[dd[i] >> NBSH], 1);
        tmp[p] = (u32)ss[i] | ((u32)(dd[i] & (BUCKW - 1)) << 16);
      }
    }
  }
}

// ph4: one block per bucket: fine 128-bin LDS hist + scan -> deg/dinv/meta,
// then dst-sorted csr (entry = src).
__global__ __launch_bounds__(256) void k_bucket(
    const u32* __restrict__ tmp, const int* __restrict__ bsv,
    int4* __restrict__ meta, float* __restrict__ dinv,
    u32* __restrict__ csr, int N) {
  __shared__ int hist[BUCKW];
  __shared__ int sc[BUCKW];
  __shared__ int cur[BUCKW];
  const int b = blockIdx.x, tid = threadIdx.x;
  const int s0 = bsv[b], s1 = bsv[b + 1];
  if (tid < BUCKW) hist[tid] = 0;
  __syncthreads();
  for (int base = s0 + tid; base < s1; base += 1024) {
    int tt[4];
#pragma unroll
    for (int i = 0; i < 4; i++) {
      int idx = base + i * 256;
      tt[i] = (idx < s1) ? (int)tmp[idx] : -1;
    }
#pragma unroll
    for (int i = 0; i < 4; i++)
      if (tt[i] >= 0) atomicAdd(&hist[(tt[i] >> 16) & (BUCKW - 1)], 1);
  }
  __syncthreads();
  if (tid < BUCKW) sc[tid] = hist[tid];
  __syncthreads();
#pragma unroll
  for (int o = 1; o < BUCKW; o <<= 1) {
    int t = 0;
    if (tid < BUCKW && tid >= o) t = sc[tid - o];
    __syncthreads();
    if (tid < BUCKW) sc[tid] += t;
    __syncthreads();
  }
  if (tid < BUCKW) {
    int dg = hist[tid];
    int excl = sc[tid] - dg;
    cur[tid] = excl;
    int d = (b << NBSH) + tid;
    if (d < N) {
      float dv = rsqrtf((float)dg + 1.0f);
      meta[d] = make_int4(s0 + excl, dg, __builtin_bit_cast(int, dv), 0);
      dinv[d] = dv;
    }
  }
  __syncthreads();
  for (int base = s0 + tid; base < s1; base += 1024) {
    int tt[4];
#pragma unroll
    for (int i = 0; i < 4; i++) {
      int idx = base + i * 256;
      tt[i] = (idx < s1) ? (int)tmp[idx] : -1;
    }
#pragma unroll
    for (int i = 0; i < 4; i++) {
      if (tt[i] >= 0) {
        int r = atomicAdd(&cur[(tt[i] >> 16) & (BUCKW - 1)], 1);
        csr[s0 + r] = (u32)tt[i] & 0xffffu;
      }
    }
  }
}

// ph5: pack weights: csr entry src -> src | fp16(dinv[s]*dinv[d])<<16.
__global__ __launch_bounds__(256) void k_weights(
    const int4* __restrict__ meta, const float* __restrict__ dinv,
    u32* __restrict__ csr, int N) {
  int gid = blockIdx.x * 256 + threadIdx.x;
  int r = gid >> 2, j0 = gid & 3;
  if (r >= N) return;
  int4 mt = meta[r];
  float dv = __builtin_bit_cast(float, mt.z);
  for (int j = j0; j < mt.y; j += 4) {
    u32 s = csr[mt.x + j];
    float w = dinv[s] * dv;
    csr[mt.x + j] = s | ((u32)f2h(w) << 16);
  }
}

// ---------------------------------------------------------------------------
// Gather+LN core — FP8 h rows (128 B), fp32 accumulation.
// Row owned by 16 lanes, uint2 (8 fp8) per lane.
// PER-GROUP loop bound (divergent across the wave's 4 groups): no wave-max
// shuffles in the prologue; finished groups' loads are exec-masked (no
// memory requests); deg-0/invalid rows skip the loop entirely.
#define ACC_EDGE(vv, ee)                                                     \
  {                                                                          \
    float ww = (float)__builtin_bit_cast(_Float16, (u16)((ee) >> 16));       \
    f32x2 p_;                                                                \
    p_ = __builtin_amdgcn_cvt_pk_f32_fp8(vv.x, false);                       \
    acc[0] = fmaf(p_[0], ww, acc[0]); acc[1] = fmaf(p_[1], ww, acc[1]);      \
    p_ = __builtin_amdgcn_cvt_pk_f32_fp8(vv.x, true);                        \
    acc[2] = fmaf(p_[0], ww, acc[2]); acc[3] = fmaf(p_[1], ww, acc[3]);      \
    p_ = __builtin_amdgcn_cvt_pk_f32_fp8(vv.y, false);                       \
    acc[4] = fmaf(p_[0], ww, acc[4]); acc[5] = fmaf(p_[1], ww, acc[5]);      \
    p_ = __builtin_amdgcn_cvt_pk_f32_fp8(vv.y, true);                        \
    acc[6] = fmaf(p_[0], ww, acc[6]); acc[7] = fmaf(p_[1], ww, acc[7]);      \
  }

__device__ __forceinline__ void gather_ln_core(
    const uint2* __restrict__ hb, const int4* __restrict__ meta,
    const u32* __restrict__ csr, const float* __restrict__ b,
    const float* __restrict__ g, const float* __restrict__ bln,
    int row, int n, int sl, float out[8]) {
  const bool valid = row < n;
  const int rc = valid ? row : 0;
  int4 mt = meta[rc];
  int beg = mt.x;
  int cnt = valid ? mt.y : 0;
  float dv = __builtin_bit_cast(float, mt.z);
  float sn = dv * dv;

  float acc[8];
  {
    uint2 su = hb[(size_t)rc * 16 + sl];
    f32x2 p0 = __builtin_amdgcn_cvt_pk_f32_fp8(su.x, false);
    f32x2 p1 = __builtin_amdgcn_cvt_pk_f32_fp8(su.x, true);
    f32x2 p2 = __builtin_amdgcn_cvt_pk_f32_fp8(su.y, false);
    f32x2 p3 = __builtin_amdgcn_cvt_pk_f32_fp8(su.y, true);
    acc[0] = p0[0] * sn; acc[1] = p0[1] * sn;
    acc[2] = p1[0] * sn; acc[3] = p1[1] * sn;
    acc[4] = p2[0] * sn; acc[5] = p2[1] * sn;
    acc[6] = p3[0] * sn; acc[7] = p3[1] * sn;
  }

  // divergent per-group loop: all 16 lanes of a group share cnt.
  for (int j0 = 0; j0 < cnt; j0 += 8) {
    u32 e[8];
#pragma unroll
    for (int jj = 0; jj < 8; jj++) {
      int j = j0 + jj;
      e[jj] = (j < cnt) ? csr[beg + j] : 0u;   // uniform per 16-lane group
    }
    uint2 v[8];
#pragma unroll
    for (int jj = 0; jj < 8; jj++)
      v[jj] = hb[(size_t)(e[jj] & 0xffffu) * 16 + sl];
#pragma unroll
    for (int jj = 0; jj < 8; jj++) ACC_EDGE(v[jj], e[jj]);
  }

  // ---- LayerNorm over 128 cols, 8 per lane across 16 lanes ----
  int d0 = sl * 8;
  float4 bb0 = *(const float4*)(b + d0);
  float4 bb1 = *(const float4*)(b + d0 + 4);
  float a0 = acc[0] + bb0.x, a1 = acc[1] + bb0.y;
  float a2 = acc[2] + bb0.z, a3 = acc[3] + bb0.w;
  float a4 = acc[4] + bb1.x, a5 = acc[5] + bb1.y;
  float a6 = acc[6] + bb1.z, a7 = acc[7] + bb1.w;

  float sum = ((a0 + a1) + (a2 + a3)) + ((a4 + a5) + (a6 + a7));
#pragma unroll
  for (int o = 8; o >= 1; o >>= 1) sum += __shfl_xor(sum, o, 16);
  float mu = sum * (1.0f / 128.0f);
  float e0 = a0 - mu, e1 = a1 - mu, e2 = a2 - mu, e3 = a3 - mu;
  float e4 = a4 - mu, e5 = a5 - mu, e6 = a6 - mu, e7 = a7 - mu;
  float vs = ((e0 * e0 + e1 * e1) + (e2 * e2 + e3 * e3)) +
             ((e4 * e4 + e5 * e5) + (e6 * e6 + e7 * e7));
#pragma unroll
  for (int o = 8; o >= 1; o >>= 1) vs += __shfl_xor(vs, o, 16);
  float inv = rsqrtf(vs * (1.0f / 128.0f) + EPS);

  float4 gg0 = *(const float4*)(g + d0);
  float4 gg1 = *(const float4*)(g + d0 + 4);
  float4 bl0 = *(const float4*)(bln + d0);
  float4 bl1 = *(const float4*)(bln + d0 + 4);
  out[0] = fmaxf(e0 * inv * gg0.x + bl0.x, 0.0f);
  out[1] = fmaxf(e1 * inv * gg0.y + bl0.y, 0.0f);
  out[2] = fmaxf(e2 * inv * gg0.z + bl0.z, 0.0f);
  out[3] = fmaxf(e3 * inv * gg0.w + bl0.w, 0.0f);
  out[4] = fmaxf(e4 * inv * gg1.x + bl1.x, 0.0f);
  out[5] = fmaxf(e5 * inv * gg1.y + bl1.y, 0.0f);
  out[6] = fmaxf(e6 * inv * gg1.z + bl1.z, 0.0f);
  out[7] = fmaxf(e7 * inv * gg1.w + bl1.w, 0.0f);
}

// P6a: pure gather1 + LN + ReLU -> y1 (fp16) in global. No LDS, no barrier,
// 64-VGPR target for 8 waves/SIMD residency (latency-bound random gather).
__global__ __launch_bounds__(256, 8) void k_gather1(
    const uint2* __restrict__ hb, const int4* __restrict__ meta,
    const u32* __restrict__ csr,
    const float* __restrict__ b, const float* __restrict__ g,
    const float* __restrict__ bln,
    u16* __restrict__ y1, int n) {
  const int tid = threadIdx.x;
  const int sl = tid & 15;
  const int row = blockIdx.x * 16 + (tid >> 4);
  float o[8];
  gather_ln_core(hb, meta, csr, b, g, bln, row, n, sl, o);
  if (row >= n) return;
  uint4 pk;
  pk.x = ((u32)f2h(o[1]) << 16) | (u32)f2h(o[0]);
  pk.y = ((u32)f2h(o[3]) << 16) | (u32)f2h(o[2]);
  pk.z = ((u32)f2h(o[5]) << 16) | (u32)f2h(o[4]);
  pk.w = ((u32)f2h(o[7]) << 16) | (u32)f2h(o[6]);
  *(uint4*)(y1 + (size_t)row * D + sl * 8) = pk;
}

// P6b: standalone GEMM2: y1 (fp16) @ W2 -> B (h2, fp8).
__global__ __launch_bounds__(256) void k_gemm2(const u16* __restrict__ y1,
                                               const u16* __restrict__ Wt2,
                                               u8* __restrict__ outB, int n) {
  gemm_body<false>(y1, Wt2, outB, n, blockIdx.x);
}

// P7: gather2 + LN + ReLU + residual -> fp32 out. Residual read and final
// store are non-temporal (pure streaming) so 51MB of fp32 traffic doesn't
// evict the B rows from L2.
__global__ __launch_bounds__(256, 8) void k_gather2(
    const uint2* __restrict__ hb, const int4* __restrict__ meta,
    const u32* __restrict__ csr,
    const float* __restrict__ b, const float* __restrict__ g,
    const float* __restrict__ bln, const float* __restrict__ resid,
    float* __restrict__ outf, int n) {
  const int tid = threadIdx.x;
  const int sl = tid & 15;
  const int row = blockIdx.x * 16 + (tid >> 4);
  float o[8];
  gather_ln_core(hb, meta, csr, b, g, bln, row, n, sl, o);
  if (row >= n) return;
  size_t base = (size_t)row * D + sl * 8;
  f32x4 r0 = __builtin_nontemporal_load((const f32x4*)(resid + base));
  f32x4 r1 = __builtin_nontemporal_load((const f32x4*)(resid + base + 4));
  f32x4 w0, w1;
  w0[0] = o[0] + r0[0]; w0[1] = o[1] + r0[1];
  w0[2] = o[2] + r0[2]; w0[3] = o[3] + r0[3];
  w1[0] = o[4] + r1[0]; w1[1] = o[5] + r1[1];
  w1[2] = o[6] + r1[2]; w1[3] = o[7] + r1[3];
  __builtin_nontemporal_store(w0, (f32x4*)(outf + base));
  __builtin_nontemporal_store(w1, (f32x4*)(outf + base + 4));
}

// ---------------------------------------------------------------------------
extern "C" void kernel_launch(void* const* d_in, const int* in_sizes, int n_in,
                              void* d_out, int out_size, void* d_ws, size_t ws_size,
                              hipStream_t stream) {
  const float* x    = (const float*)d_in[0];
  const int*   ei   = (const int*)d_in[1];
  const float* W1   = (const float*)d_in[2];
  const float* b1   = (const float*)d_in[3];
  const float* g1   = (const float*)d_in[4];
  const float* bl1  = (const float*)d_in[5];
  const float* W2   = (const float*)d_in[6];
  const float* b2   = (const float*)d_in[7];
  const float* g2   = (const float*)d_in[8];
  const float* bl2  = (const float*)d_in[9];

  const int N = in_sizes[0] / D;
  const int E = in_sizes[1] / 2;
  const int* src = ei;
  const int* dst = ei + E;

  const int NB  = (N + BUCKW - 1) / BUCKW;  // coarse buckets
  const int M   = NB * KB;
  const int EPB = (E + KB - 1) / KB;        // edges per count/scatter block
  const int GB  = (N + 63) / 64;            // gemm blocks
  const int RB  = (N + 15) / 16;            // gather blocks (16 rows each)
  const int SB  = (M + 1023) / 1024;        // scan blocks

  size_t off = 0;
  auto walloc = [&](size_t bytes) {
    void* p = (char*)d_ws + off;
    off = (off + bytes + 255) & ~(size_t)255;
    return p;
  };
  int*   cnt   = (int*)walloc((size_t)M * 4);
  int*   bsum  = (int*)walloc((size_t)SB * 4);
  int*   bsv   = (int*)walloc((size_t)(NB + 1) * 4);
  u32*   tmp   = (u32*)walloc((size_t)E * 4);
  u32*   csr   = (u32*)walloc((size_t)E * 4);
  int4*  meta  = (int4*)walloc((size_t)N * 16);
  float* dinv  = (float*)walloc((size_t)N * 4);
  u8*    A     = (u8*)walloc((size_t)N * D);        // h1 (fp8 e4m3)
  u8*    B     = (u8*)walloc((size_t)N * D);        // h2 (fp8 e4m3)
  u16*   Wt1   = (u16*)walloc((size_t)D * D * 2);
  u16*   Wt2   = (u16*)walloc((size_t)D * D * 2);
  u16*   y1    = (u16*)walloc((size_t)N * D * 2);   // LN1 out (fp16)
  float* O     = (float*)d_out;

  // P0: weight converts
  k_prep<<<(2 * D * D + 255) / 256, 256, 0, stream>>>(W1, W2, Wt1, Wt2);
  // ph1: coarse count || GEMM1 (x @ W1 -> A fp8)
  k_count_gemm1<<<KB + GB, 256, 0, stream>>>(dst, cnt, E, NB, EPB, x, Wt1, A, N);
  // ph2: parallel scan (reduce -> apply-with-inline-mid)
  k_scan_reduce<<<SB, 256, 0, stream>>>(cnt, M, bsum);
  k_scan_apply<<<SB, 256, 0, stream>>>(cnt, M, bsum, bsv, NB, E);
  // ph3: scatter into buckets
  k_scatter<<<KB, 256, 0, stream>>>(src, dst, cnt, tmp, E, NB, EPB);
  // ph4: per-bucket fine sort -> csr + meta + dinv
  k_bucket<<<NB, 256, 0, stream>>>(tmp, bsv, meta, dinv, csr, N);
  // ph5: pack weights
  k_weights<<<(N * 4 + 255) / 256, 256, 0, stream>>>(meta, dinv, csr, N);
  // P6a: gather1 + LN + ReLU -> y1 (fp16)
  k_gather1<<<RB, 256, 0, stream>>>((const uint2*)A, meta, csr, b1, g1, bl1,
                                    y1, N);
  // P6b: GEMM2 -> B (fp8)
  k_gemm2<<<GB, 256, 0, stream>>>(y1, Wt2, B, N);
  // P7: gather2 + LN + ReLU + residual -> O
  k_gather2<<<RB, 256, 0, stream>>>((const uint2*)B, meta, csr,
                                    b2, g2, bl2, x, O, N);
}

// Round 12
// 190.741 us; speedup vs baseline: 1.8834x; 1.0031x over previous
//
#include <hip/hip_runtime.h>
#include <hip/hip_fp16.h>

#define D 128
#define EPS 1e-5f
#define KB 256         // coarse count/scatter blocks
#define KBSH 8         // log2(KB)
#define NBSH 7         // bucket = dst >> 7
#define BUCKW 128      // dsts per bucket

typedef unsigned int u32;
typedef unsigned short u16;
typedef unsigned char u8;
typedef __attribute__((ext_vector_type(8))) _Float16 half8;  // mfma A/B frag
typedef __attribute__((ext_vector_type(4))) float f32x4;
typedef __attribute__((ext_vector_type(2))) float f32x2;

__device__ inline u16 f2h(float x) {
  _Float16 t = (_Float16)x;
  return __builtin_bit_cast(u16, t);
}
__device__ inline u8 f2fp8(float x) {
  return (u8)(__builtin_amdgcn_cvt_pk_fp8_f32(x, x, 0, false) & 0xff);
}

// ---------------------------------------------------------------------------
// P0: convert W1,W2 fp32[k][c] -> fp16 Wt[c][k].
__global__ __launch_bounds__(256) void k_prep(const float* __restrict__ W1,
                                              const float* __restrict__ W2,
                                              u16* __restrict__ Wt1,
                                              u16* __restrict__ Wt2) {
  int i = blockIdx.x * 256 + threadIdx.x;
  if (i < 2 * D * D) {
    const float* W = (i < D * D) ? W1 : W2;
    u16* Wt = (i < D * D) ? Wt1 : Wt2;
    int ii = i & (D * D - 1);
    int k = ii >> 7, c = ii & 127;
    Wt[c * D + k] = f2h(W[ii]);
  }
}

// ---------------------------------------------------------------------------
// LDS-free MFMA GEMM body; OUTPUT IS FP8 (e4m3). 32 rows per block:
// 4 waves = 2 row-halves x 2 ct-halves (2x the blocks of the 64-row tile,
// for latency hiding on the A-fragment HBM loads). Per-element MFMA order
// identical to the 64-row version -> bit-identical output.
template <bool F32IN>
__device__ __forceinline__ void gemm_body(const void* __restrict__ in_,
                                          const u16* __restrict__ Wt,
                                          u8* __restrict__ out, int nrows,
                                          int blk) {
  const int tid = threadIdx.x;
  const int lane = tid & 63, wv = tid >> 6;
  const int m = lane & 15, q = lane >> 4;
  const int r0 = blk * 32 + (wv & 1) * 16;
  const int ch = wv >> 1;                      // ct = ch*4 + c
  const int rowa = min(r0 + m, nrows - 1);

  f32x4 acc[4];
#pragma unroll
  for (int c = 0; c < 4; c++) acc[c] = (f32x4)(0.0f);

#pragma unroll
  for (int kk = 0; kk < 4; kk++) {
    const int kbase = kk * 32 + q * 8;
    half8 a;
    if (F32IN) {
      const float* in = (const float*)in_;
      float4 v0 = *(const float4*)(in + (size_t)rowa * D + kbase);
      float4 v1 = *(const float4*)(in + (size_t)rowa * D + kbase + 4);
      a[0] = (_Float16)v0.x; a[1] = (_Float16)v0.y;
      a[2] = (_Float16)v0.z; a[3] = (_Float16)v0.w;
      a[4] = (_Float16)v1.x; a[5] = (_Float16)v1.y;
      a[6] = (_Float16)v1.z; a[7] = (_Float16)v1.w;
    } else {
      const u16* in = (const u16*)in_;
      a = *(const half8*)(in + (size_t)rowa * D + kbase);
    }
#pragma unroll
    for (int c = 0; c < 4; c++) {
      int ct = ch * 4 + c;
      half8 b = *(const half8*)(Wt + (ct * 16 + m) * D + kbase);
      acc[c] = __builtin_amdgcn_mfma_f32_16x16x32_f16(a, b, acc[c], 0, 0, 0);
    }
  }

#pragma unroll
  for (int c = 0; c < 4; c++) {
    int ct = ch * 4 + c;
#pragma unroll
    for (int rg = 0; rg < 4; rg++) {
      int rr = r0 + q * 4 + rg;
      if (rr < nrows) out[(size_t)rr * D + ct * 16 + m] = f2fp8(acc[c][rg]);
    }
  }
}

// ph1: coarse-bucket count, 8-deep batched (blocks [0,KB)) || GEMM1.
__global__ __launch_bounds__(256) void k_count_gemm1(
    const int* __restrict__ dst, int* __restrict__ cnt, int E, int NB, int EPB,
    const float* __restrict__ x, const u16* __restrict__ Wt1,
    u8* __restrict__ A, int nrows) {
  if (blockIdx.x < (u32)KB) {
    __shared__ int hist[512];
    const int k = blockIdx.x, tid = threadIdx.x;
    for (int i = tid; i < NB; i += 256) hist[i] = 0;
    __syncthreads();
    const int e0 = k * EPB, e1 = min(E, e0 + EPB);
    for (int base = e0 + tid; base < e1; base += 2048) {
      int dd[8];
#pragma unroll
      for (int i = 0; i < 8; i++) {
        int e = base + i * 256;
        dd[i] = (e < e1) ? dst[e] : -1;
      }
#pragma unroll
      for (int i = 0; i < 8; i++)
        if (dd[i] >= 0) atomicAdd(&hist[dd[i] >> NBSH], 1);
    }
    __syncthreads();
    for (int b = tid; b < NB; b += 256) cnt[b * KB + k] = hist[b];
  } else {
    gemm_body<true>(x, Wt1, A, nrows, blockIdx.x - KB);
  }
}

// ph2a: per-block (1024 elem) reduce -> bsum.
__global__ __launch_bounds__(256) void k_scan_reduce(
    const int* __restrict__ cnt, int M, int* __restrict__ bsum) {
  const int b = blockIdx.x, t = threadIdx.x;
  const int lane = t & 63, w = t >> 6;
  int idx = b * 1024 + t * 4;
  int4 v = make_int4(0, 0, 0, 0);
  if (idx + 3 < M) {
    v = *(const int4*)(cnt + idx);
  } else {
    if (idx + 0 < M) v.x = cnt[idx + 0];
    if (idx + 1 < M) v.y = cnt[idx + 1];
    if (idx + 2 < M) v.z = cnt[idx + 2];
  }
  int s = v.x + v.y + v.z + v.w;
#pragma unroll
  for (int o = 1; o < 64; o <<= 1) s += __shfl_xor(s, o, 64);
  __shared__ int ws[4];
  if (lane == 0) ws[w] = s;
  __syncthreads();
  if (t == 0) bsum[b] = ws[0] + ws[1] + ws[2] + ws[3];
}

// ph2b: per-block local scan; block offset = sum of bsum[0..b-1] (inline mid).
__global__ __launch_bounds__(256) void k_scan_apply(
    int* __restrict__ cnt, int M, const int* __restrict__ bsum,
    int* __restrict__ bsv, int NB, int E) {
  const int b = blockIdx.x, t = threadIdx.x;
  const int lane = t & 63, w = t >> 6;
  if (b == 0 && t == 0) bsv[NB] = E;
  int idx = b * 1024 + t * 4;
  int4 v = make_int4(0, 0, 0, 0);
  if (idx + 3 < M) {
    v = *(const int4*)(cnt + idx);
  } else {
    if (idx + 0 < M) v.x = cnt[idx + 0];
    if (idx + 1 < M) v.y = cnt[idx + 1];
    if (idx + 2 < M) v.z = cnt[idx + 2];
  }
  int s = v.x + v.y + v.z + v.w;
  int incl = s;
#pragma unroll
  for (int o = 1; o < 64; o <<= 1) {
    int u = __shfl_up(incl, o, 64);
    if (lane >= o) incl += u;
  }
  __shared__ int ws[4];
  __shared__ int sboff;
  if (lane == 63) ws[w] = incl;
  if (t < 64) {
    int partial = 0;
    for (int j = t; j < b; j += 64) partial += bsum[j];
#pragma unroll
    for (int o = 32; o >= 1; o >>= 1) partial += __shfl_xor(partial, o, 64);
    if (t == 0) sboff = partial;
  }
  __syncthreads();
  int wbase = 0;
#pragma unroll
  for (int j = 0; j < 4; j++)
    if (j < w) wbase += ws[j];
  int base = sboff + wbase + incl - s;  // exclusive prefix for idx
  int e0 = base, e1 = e0 + v.x, e2 = e1 + v.y, e3 = e2 + v.z;
  // idx is a multiple of 4; only idx itself can be a multiple of KB.
  if (idx < M) {
    cnt[idx] = e0;
    if ((idx & (KB - 1)) == 0) bsv[idx >> KBSH] = e0;
  }
  if (idx + 1 < M) cnt[idx + 1] = e1;
  if (idx + 2 < M) cnt[idx + 2] = e2;
  if (idx + 3 < M) cnt[idx + 3] = e3;
}

// ph3: scatter edges into bucket-grouped tmp via LDS cursors, 8-deep batched.
__global__ __launch_bounds__(256) void k_scatter(
    const int* __restrict__ src, const int* __restrict__ dst,
    const int* __restrict__ cnt, u32* __restrict__ tmp, int E, int NB,
    int EPB) {
  __shared__ int off[512];
  const int k = blockIdx.x, tid = threadIdx.x;
  for (int b = tid; b < NB; b += 256) off[b] = cnt[b * KB + k];
  __syncthreads();
  const int e0 = k * EPB, e1 = min(E, e0 + EPB);
  for (int base = e0 + tid; base < e1; base += 2048) {
    int dd[8], ss[8];
#pragma unroll
    for (int i = 0; i < 8; i++) {
      int e = base + i * 256;
      dd[i] = (e < e1) ? dst[e] : -1;
      ss[i] = (e < e1) ? src[e] : 0;
    }
#pragma unroll
    for (int i = 0; i < 8; i++) {
      if (dd[i] >= 0) {
        int p = atomicAdd(&off[dd[i] >> NBSH], 1);
        tmp[p] = (u32)ss[i] | ((u32)(dd[i] & (BUCKW - 1)) << 16);
      }
    }
  }
}

// ph4: one block per bucket: fine 128-bin LDS hist + scan -> deg/dinv/meta,
// then dst-sorted csr (entry = src).
__global__ __launch_bounds__(256) void k_bucket(
    const u32* __restrict__ tmp, const int* __restrict__ bsv,
    int4* __restrict__ meta, float* __restrict__ dinv,
    u32* __restrict__ csr, int N) {
  __shared__ int hist[BUCKW];
  __shared__ int sc[BUCKW];
  __shared__ int cur[BUCKW];
  const int b = blockIdx.x, tid = threadIdx.x;
  const int s0 = bsv[b], s1 = bsv[b + 1];
  if (tid < BUCKW) hist[tid] = 0;
  __syncthreads();
  for (int base = s0 + tid; base < s1; base += 1024) {
    int tt[4];
#pragma unroll
    for (int i = 0; i < 4; i++) {
      int idx = base + i * 256;
      tt[i] = (idx < s1) ? (int)tmp[idx] : -1;
    }
#pragma unroll
    for (int i = 0; i < 4; i++)
      if (tt[i] >= 0) atomicAdd(&hist[(tt[i] >> 16) & (BUCKW - 1)], 1);
  }
  __syncthreads();
  if (tid < BUCKW) sc[tid] = hist[tid];
  __syncthreads();
#pragma unroll
  for (int o = 1; o < BUCKW; o <<= 1) {
    int t = 0;
    if (tid < BUCKW && tid >= o) t = sc[tid - o];
    __syncthreads();
    if (tid < BUCKW) sc[tid] += t;
    __syncthreads();
  }
  if (tid < BUCKW) {
    int dg = hist[tid];
    int excl = sc[tid] - dg;
    cur[tid] = excl;
    int d = (b << NBSH) + tid;
    if (d < N) {
      float dv = rsqrtf((float)dg + 1.0f);
      meta[d] = make_int4(s0 + excl, dg, __builtin_bit_cast(int, dv), 0);
      dinv[d] = dv;
    }
  }
  __syncthreads();
  for (int base = s0 + tid; base < s1; base += 1024) {
    int tt[4];
#pragma unroll
    for (int i = 0; i < 4; i++) {
      int idx = base + i * 256;
      tt[i] = (idx < s1) ? (int)tmp[idx] : -1;
    }
#pragma unroll
    for (int i = 0; i < 4; i++) {
      if (tt[i] >= 0) {
        int r = atomicAdd(&cur[(tt[i] >> 16) & (BUCKW - 1)], 1);
        csr[s0 + r] = (u32)tt[i] & 0xffffu;
      }
    }
  }
}

// ph5: pack weights: csr entry src -> src | fp16(dinv[s]*dinv[d])<<16.
__global__ __launch_bounds__(256) void k_weights(
    const int4* __restrict__ meta, const float* __restrict__ dinv,
    u32* __restrict__ csr, int N) {
  int gid = blockIdx.x * 256 + threadIdx.x;
  int r = gid >> 2, j0 = gid & 3;
  if (r >= N) return;
  int4 mt = meta[r];
  float dv = __builtin_bit_cast(float, mt.z);
  for (int j = j0; j < mt.y; j += 4) {
    u32 s = csr[mt.x + j];
    float w = dinv[s] * dv;
    csr[mt.x + j] = s | ((u32)f2h(w) << 16);
  }
}

// ---------------------------------------------------------------------------
// Gather+LN core — FP8 h rows (128 B), fp32 accumulation.
// Row owned by 16 lanes, uint2 (8 fp8) per lane.
// PER-GROUP loop bound (divergent across the wave's 4 groups): no wave-max
// shuffles in the prologue; finished groups' loads are exec-masked (no
// memory requests); deg-0/invalid rows skip the loop entirely.
#define ACC_EDGE(vv, ee)                                                     \
  {                                                                          \
    float ww = (float)__builtin_bit_cast(_Float16, (u16)((ee) >> 16));       \
    f32x2 p_;                                                                \
    p_ = __builtin_amdgcn_cvt_pk_f32_fp8(vv.x, false);                       \
    acc[0] = fmaf(p_[0], ww, acc[0]); acc[1] = fmaf(p_[1], ww, acc[1]);      \
    p_ = __builtin_amdgcn_cvt_pk_f32_fp8(vv.x, true);                        \
    acc[2] = fmaf(p_[0], ww, acc[2]); acc[3] = fmaf(p_[1], ww, acc[3]);      \
    p_ = __builtin_amdgcn_cvt_pk_f32_fp8(vv.y, false);                       \
    acc[4] = fmaf(p_[0], ww, acc[4]); acc[5] = fmaf(p_[1], ww, acc[5]);      \
    p_ = __builtin_amdgcn_cvt_pk_f32_fp8(vv.y, true);                        \
    acc[6] = fmaf(p_[0], ww, acc[6]); acc[7] = fmaf(p_[1], ww, acc[7]);      \
  }

__device__ __forceinline__ void gather_ln_core(
    const uint2* __restrict__ hb, const int4* __restrict__ meta,
    const u32* __restrict__ csr, const float* __restrict__ b,
    const float* __restrict__ g, const float* __restrict__ bln,
    int row, int n, int sl, float out[8]) {
  const bool valid = row < n;
  const int rc = valid ? row : 0;
  int4 mt = meta[rc];
  int beg = mt.x;
  int cnt = valid ? mt.y : 0;
  float dv = __builtin_bit_cast(float, mt.z);
  float sn = dv * dv;

  float acc[8];
  {
    uint2 su = hb[(size_t)rc * 16 + sl];
    f32x2 p0 = __builtin_amdgcn_cvt_pk_f32_fp8(su.x, false);
    f32x2 p1 = __builtin_amdgcn_cvt_pk_f32_fp8(su.x, true);
    f32x2 p2 = __builtin_amdgcn_cvt_pk_f32_fp8(su.y, false);
    f32x2 p3 = __builtin_amdgcn_cvt_pk_f32_fp8(su.y, true);
    acc[0] = p0[0] * sn; acc[1] = p0[1] * sn;
    acc[2] = p1[0] * sn; acc[3] = p1[1] * sn;
    acc[4] = p2[0] * sn; acc[5] = p2[1] * sn;
    acc[6] = p3[0] * sn; acc[7] = p3[1] * sn;
  }

  // divergent per-group loop: all 16 lanes of a group share cnt.
  for (int j0 = 0; j0 < cnt; j0 += 8) {
    u32 e[8];
#pragma unroll
    for (int jj = 0; jj < 8; jj++) {
      int j = j0 + jj;
      e[jj] = (j < cnt) ? csr[beg + j] : 0u;   // uniform per 16-lane group
    }
    uint2 v[8];
#pragma unroll
    for (int jj = 0; jj < 8; jj++)
      v[jj] = hb[(size_t)(e[jj] & 0xffffu) * 16 + sl];
#pragma unroll
    for (int jj = 0; jj < 8; jj++) ACC_EDGE(v[jj], e[jj]);
  }

  // ---- LayerNorm over 128 cols, 8 per lane across 16 lanes ----
  int d0 = sl * 8;
  float4 bb0 = *(const float4*)(b + d0);
  float4 bb1 = *(const float4*)(b + d0 + 4);
  float a0 = acc[0] + bb0.x, a1 = acc[1] + bb0.y;
  float a2 = acc[2] + bb0.z, a3 = acc[3] + bb0.w;
  float a4 = acc[4] + bb1.x, a5 = acc[5] + bb1.y;
  float a6 = acc[6] + bb1.z, a7 = acc[7] + bb1.w;

  float sum = ((a0 + a1) + (a2 + a3)) + ((a4 + a5) + (a6 + a7));
#pragma unroll
  for (int o = 8; o >= 1; o >>= 1) sum += __shfl_xor(sum, o, 16);
  float mu = sum * (1.0f / 128.0f);
  float e0 = a0 - mu, e1 = a1 - mu, e2 = a2 - mu, e3 = a3 - mu;
  float e4 = a4 - mu, e5 = a5 - mu, e6 = a6 - mu, e7 = a7 - mu;
  float vs = ((e0 * e0 + e1 * e1) + (e2 * e2 + e3 * e3)) +
             ((e4 * e4 + e5 * e5) + (e6 * e6 + e7 * e7));
#pragma unroll
  for (int o = 8; o >= 1; o >>= 1) vs += __shfl_xor(vs, o, 16);
  float inv = rsqrtf(vs * (1.0f / 128.0f) + EPS);

  float4 gg0 = *(const float4*)(g + d0);
  float4 gg1 = *(const float4*)(g + d0 + 4);
  float4 bl0 = *(const float4*)(bln + d0);
  float4 bl1 = *(const float4*)(bln + d0 + 4);
  out[0] = fmaxf(e0 * inv * gg0.x + bl0.x, 0.0f);
  out[1] = fmaxf(e1 * inv * gg0.y + bl0.y, 0.0f);
  out[2] = fmaxf(e2 * inv * gg0.z + bl0.z, 0.0f);
  out[3] = fmaxf(e3 * inv * gg0.w + bl0.w, 0.0f);
  out[4] = fmaxf(e4 * inv * gg1.x + bl1.x, 0.0f);
  out[5] = fmaxf(e5 * inv * gg1.y + bl1.y, 0.0f);
  out[6] = fmaxf(e6 * inv * gg1.z + bl1.z, 0.0f);
  out[7] = fmaxf(e7 * inv * gg1.w + bl1.w, 0.0f);
}

// P6a: pure gather1 + LN + ReLU -> y1 (fp16) in global. No LDS, no barrier,
// 64-VGPR target for 8 waves/SIMD residency (latency-bound random gather).
__global__ __launch_bounds__(256, 8) void k_gather1(
    const uint2* __restrict__ hb, const int4* __restrict__ meta,
    const u32* __restrict__ csr,
    const float* __restrict__ b, const float* __restrict__ g,
    const float* __restrict__ bln,
    u16* __restrict__ y1, int n) {
  const int tid = threadIdx.x;
  const int sl = tid & 15;
  const int row = blockIdx.x * 16 + (tid >> 4);
  float o[8];
  gather_ln_core(hb, meta, csr, b, g, bln, row, n, sl, o);
  if (row >= n) return;
  uint4 pk;
  pk.x = ((u32)f2h(o[1]) << 16) | (u32)f2h(o[0]);
  pk.y = ((u32)f2h(o[3]) << 16) | (u32)f2h(o[2]);
  pk.z = ((u32)f2h(o[5]) << 16) | (u32)f2h(o[4]);
  pk.w = ((u32)f2h(o[7]) << 16) | (u32)f2h(o[6]);
  *(uint4*)(y1 + (size_t)row * D + sl * 8) = pk;
}

// P6b: standalone GEMM2: y1 (fp16) @ W2 -> B (h2, fp8).
__global__ __launch_bounds__(256) void k_gemm2(const u16* __restrict__ y1,
                                               const u16* __restrict__ Wt2,
                                               u8* __restrict__ outB, int n) {
  gemm_body<false>(y1, Wt2, outB, n, blockIdx.x);
}

// P7: gather2 + LN + ReLU + residual -> fp32 out. Residual read and final
// store are non-temporal (pure streaming) so 51MB of fp32 traffic doesn't
// evict the B rows from L2.
__global__ __launch_bounds__(256, 8) void k_gather2(
    const uint2* __restrict__ hb, const int4* __restrict__ meta,
    const u32* __restrict__ csr,
    const float* __restrict__ b, const float* __restrict__ g,
    const float* __restrict__ bln, const float* __restrict__ resid,
    float* __restrict__ outf, int n) {
  const int tid = threadIdx.x;
  const int sl = tid & 15;
  const int row = blockIdx.x * 16 + (tid >> 4);
  float o[8];
  gather_ln_core(hb, meta, csr, b, g, bln, row, n, sl, o);
  if (row >= n) return;
  size_t base = (size_t)row * D + sl * 8;
  f32x4 r0 = __builtin_nontemporal_load((const f32x4*)(resid + base));
  f32x4 r1 = __builtin_nontemporal_load((const f32x4*)(resid + base + 4));
  f32x4 w0, w1;
  w0[0] = o[0] + r0[0]; w0[1] = o[1] + r0[1];
  w0[2] = o[2] + r0[2]; w0[3] = o[3] + r0[3];
  w1[0] = o[4] + r1[0]; w1[1] = o[5] + r1[1];
  w1[2] = o[6] + r1[2]; w1[3] = o[7] + r1[3];
  __builtin_nontemporal_store(w0, (f32x4*)(outf + base));
  __builtin_nontemporal_store(w1, (f32x4*)(outf + base + 4));
}

// ---------------------------------------------------------------------------
extern "C" void kernel_launch(void* const* d_in, const int* in_sizes, int n_in,
                              void* d_out, int out_size, void* d_ws, size_t ws_size,
                              hipStream_t stream) {
  const float* x    = (const float*)d_in[0];
  const int*   ei   = (const int*)d_in[1];
  const float* W1   = (const float*)d_in[2];
  const float* b1   = (const float*)d_in[3];
  const float* g1   = (const float*)d_in[4];
  const float* bl1  = (const float*)d_in[5];
  const float* W2   = (const float*)d_in[6];
  const float* b2   = (const float*)d_in[7];
  const float* g2   = (const float*)d_in[8];
  const float* bl2  = (const float*)d_in[9];

  const int N = in_sizes[0] / D;
  const int E = in_sizes[1] / 2;
  const int* src = ei;
  const int* dst = ei + E;

  const int NB  = (N + BUCKW - 1) / BUCKW;  // coarse buckets
  const int M   = NB * KB;
  const int EPB = (E + KB - 1) / KB;        // edges per count/scatter block
  const int GB  = (N + 31) / 32;            // gemm blocks (32 rows each)
  const int RB  = (N + 15) / 16;            // gather blocks (16 rows each)
  const int SB  = (M + 1023) / 1024;        // scan blocks

  size_t off = 0;
  auto walloc = [&](size_t bytes) {
    void* p = (char*)d_ws + off;
    off = (off + bytes + 255) & ~(size_t)255;
    return p;
  };
  int*   cnt   = (int*)walloc((size_t)M * 4);
  int*   bsum  = (int*)walloc((size_t)SB * 4);
  int*   bsv   = (int*)walloc((size_t)(NB + 1) * 4);
  u32*   tmp   = (u32*)walloc((size_t)E * 4);
  u32*   csr   = (u32*)walloc((size_t)E * 4);
  int4*  meta  = (int4*)walloc((size_t)N * 16);
  float* dinv  = (float*)walloc((size_t)N * 4);
  u8*    A     = (u8*)walloc((size_t)N * D);        // h1 (fp8 e4m3)
  u8*    B     = (u8*)walloc((size_t)N * D);        // h2 (fp8 e4m3)
  u16*   Wt1   = (u16*)walloc((size_t)D * D * 2);
  u16*   Wt2   = (u16*)walloc((size_t)D * D * 2);
  u16*   y1    = (u16*)walloc((size_t)N * D * 2);   // LN1 out (fp16)
  float* O     = (float*)d_out;

  // P0: weight converts
  k_prep<<<(2 * D * D + 255) / 256, 256, 0, stream>>>(W1, W2, Wt1, Wt2);
  // ph1: coarse count || GEMM1 (x @ W1 -> A fp8)
  k_count_gemm1<<<KB + GB, 256, 0, stream>>>(dst, cnt, E, NB, EPB, x, Wt1, A, N);
  // ph2: parallel scan (reduce -> apply-with-inline-mid)
  k_scan_reduce<<<SB, 256, 0, stream>>>(cnt, M, bsum);
  k_scan_apply<<<SB, 256, 0, stream>>>(cnt, M, bsum, bsv, NB, E);
  // ph3: scatter into buckets
  k_scatter<<<KB, 256, 0, stream>>>(src, dst, cnt, tmp, E, NB, EPB);
  // ph4: per-bucket fine sort -> csr + meta + dinv
  k_bucket<<<NB, 256, 0, stream>>>(tmp, bsv, meta, dinv, csr, N);
  // ph5: pack weights
  k_weights<<<(N * 4 + 255) / 256, 256, 0, stream>>>(meta, dinv, csr, N);
  // P6a: gather1 + LN + ReLU -> y1 (fp16)
  k_gather1<<<RB, 256, 0, stream>>>((const uint2*)A, meta, csr, b1, g1, bl1,
                                    y1, N);
  // P6b: GEMM2 -> B (fp8)
  k_gemm2<<<GB, 256, 0, stream>>>(y1, Wt2, B, N);
  // P7: gather2 + LN + ReLU + residual -> O
  k_gather2<<<RB, 256, 0, stream>>>((const uint2*)B, meta, csr,
                                    b2, g2, bl2, x, O, N);
}

// Round 13
// 188.811 us; speedup vs baseline: 1.9027x; 1.0102x over previous
//
#include <hip/hip_runtime.h>
#include <hip/hip_fp16.h>

#define D 128
#define EPS 1e-5f
#define KB 256         // coarse count/scatter blocks
#define KBSH 8         // log2(KB)
#define NBSH 7         // bucket = dst >> 7
#define BUCKW 128      // dsts per bucket

typedef unsigned int u32;
typedef unsigned short u16;
typedef unsigned char u8;
typedef __attribute__((ext_vector_type(8))) _Float16 half8;  // mfma A/B frag
typedef __attribute__((ext_vector_type(4))) float f32x4;
typedef __attribute__((ext_vector_type(2))) float f32x2;

__device__ inline u16 f2h(float x) {
  _Float16 t = (_Float16)x;
  return __builtin_bit_cast(u16, t);
}
__device__ inline u8 f2fp8(float x) {
  return (u8)(__builtin_amdgcn_cvt_pk_fp8_f32(x, x, 0, false) & 0xff);
}

// ---------------------------------------------------------------------------
// P0: convert W1,W2 fp32[k][c] -> fp16 Wt[c][k].
__global__ __launch_bounds__(256) void k_prep(const float* __restrict__ W1,
                                              const float* __restrict__ W2,
                                              u16* __restrict__ Wt1,
                                              u16* __restrict__ Wt2) {
  int i = blockIdx.x * 256 + threadIdx.x;
  if (i < 2 * D * D) {
    const float* W = (i < D * D) ? W1 : W2;
    u16* Wt = (i < D * D) ? Wt1 : Wt2;
    int ii = i & (D * D - 1);
    int k = ii >> 7, c = ii & 127;
    Wt[c * D + k] = f2h(W[ii]);
  }
}

// ---------------------------------------------------------------------------
// LDS-free MFMA GEMM body; OUTPUT IS FP8 (e4m3). 32 rows per block:
// 4 waves = 2 row-halves x 2 ct-halves. Per-element MFMA order identical
// to the 64-row version -> bit-identical output.
template <bool F32IN>
__device__ __forceinline__ void gemm_body(const void* __restrict__ in_,
                                          const u16* __restrict__ Wt,
                                          u8* __restrict__ out, int nrows,
                                          int blk) {
  const int tid = threadIdx.x;
  const int lane = tid & 63, wv = tid >> 6;
  const int m = lane & 15, q = lane >> 4;
  const int r0 = blk * 32 + (wv & 1) * 16;
  const int ch = wv >> 1;                      // ct = ch*4 + c
  const int rowa = min(r0 + m, nrows - 1);

  f32x4 acc[4];
#pragma unroll
  for (int c = 0; c < 4; c++) acc[c] = (f32x4)(0.0f);

#pragma unroll
  for (int kk = 0; kk < 4; kk++) {
    const int kbase = kk * 32 + q * 8;
    half8 a;
    if (F32IN) {
      const float* in = (const float*)in_;
      float4 v0 = *(const float4*)(in + (size_t)rowa * D + kbase);
      float4 v1 = *(const float4*)(in + (size_t)rowa * D + kbase + 4);
      a[0] = (_Float16)v0.x; a[1] = (_Float16)v0.y;
      a[2] = (_Float16)v0.z; a[3] = (_Float16)v0.w;
      a[4] = (_Float16)v1.x; a[5] = (_Float16)v1.y;
      a[6] = (_Float16)v1.z; a[7] = (_Float16)v1.w;
    } else {
      const u16* in = (const u16*)in_;
      a = *(const half8*)(in + (size_t)rowa * D + kbase);
    }
#pragma unroll
    for (int c = 0; c < 4; c++) {
      int ct = ch * 4 + c;
      half8 b = *(const half8*)(Wt + (ct * 16 + m) * D + kbase);
      acc[c] = __builtin_amdgcn_mfma_f32_16x16x32_f16(a, b, acc[c], 0, 0, 0);
    }
  }

#pragma unroll
  for (int c = 0; c < 4; c++) {
    int ct = ch * 4 + c;
#pragma unroll
    for (int rg = 0; rg < 4; rg++) {
      int rr = r0 + q * 4 + rg;
      if (rr < nrows) out[(size_t)rr * D + ct * 16 + m] = f2fp8(acc[c][rg]);
    }
  }
}

// ph1: coarse-bucket count, 8-deep batched (blocks [0,KB)) || GEMM1.
__global__ __launch_bounds__(256) void k_count_gemm1(
    const int* __restrict__ dst, int* __restrict__ cnt, int E, int NB, int EPB,
    const float* __restrict__ x, const u16* __restrict__ Wt1,
    u8* __restrict__ A, int nrows) {
  if (blockIdx.x < (u32)KB) {
    __shared__ int hist[512];
    const int k = blockIdx.x, tid = threadIdx.x;
    for (int i = tid; i < NB; i += 256) hist[i] = 0;
    __syncthreads();
    const int e0 = k * EPB, e1 = min(E, e0 + EPB);
    for (int base = e0 + tid; base < e1; base += 2048) {
      int dd[8];
#pragma unroll
      for (int i = 0; i < 8; i++) {
        int e = base + i * 256;
        dd[i] = (e < e1) ? dst[e] : -1;
      }
#pragma unroll
      for (int i = 0; i < 8; i++)
        if (dd[i] >= 0) atomicAdd(&hist[dd[i] >> NBSH], 1);
    }
    __syncthreads();
    for (int b = tid; b < NB; b += 256) cnt[b * KB + k] = hist[b];
  } else {
    gemm_body<true>(x, Wt1, A, nrows, blockIdx.x - KB);
  }
}

// ph2a: per-block (1024 elem) reduce -> bsum.
__global__ __launch_bounds__(256) void k_scan_reduce(
    const int* __restrict__ cnt, int M, int* __restrict__ bsum) {
  const int b = blockIdx.x, t = threadIdx.x;
  const int lane = t & 63, w = t >> 6;
  int idx = b * 1024 + t * 4;
  int4 v = make_int4(0, 0, 0, 0);
  if (idx + 3 < M) {
    v = *(const int4*)(cnt + idx);
  } else {
    if (idx + 0 < M) v.x = cnt[idx + 0];
    if (idx + 1 < M) v.y = cnt[idx + 1];
    if (idx + 2 < M) v.z = cnt[idx + 2];
  }
  int s = v.x + v.y + v.z + v.w;
#pragma unroll
  for (int o = 1; o < 64; o <<= 1) s += __shfl_xor(s, o, 64);
  __shared__ int ws[4];
  if (lane == 0) ws[w] = s;
  __syncthreads();
  if (t == 0) bsum[b] = ws[0] + ws[1] + ws[2] + ws[3];
}

// ph2b: per-block local scan; block offset = sum of bsum[0..b-1] (inline mid).
__global__ __launch_bounds__(256) void k_scan_apply(
    int* __restrict__ cnt, int M, const int* __restrict__ bsum,
    int* __restrict__ bsv, int NB, int E) {
  const int b = blockIdx.x, t = threadIdx.x;
  const int lane = t & 63, w = t >> 6;
  if (b == 0 && t == 0) bsv[NB] = E;
  int idx = b * 1024 + t * 4;
  int4 v = make_int4(0, 0, 0, 0);
  if (idx + 3 < M) {
    v = *(const int4*)(cnt + idx);
  } else {
    if (idx + 0 < M) v.x = cnt[idx + 0];
    if (idx + 1 < M) v.y = cnt[idx + 1];
    if (idx + 2 < M) v.z = cnt[idx + 2];
  }
  int s = v.x + v.y + v.z + v.w;
  int incl = s;
#pragma unroll
  for (int o = 1; o < 64; o <<= 1) {
    int u = __shfl_up(incl, o, 64);
    if (lane >= o) incl += u;
  }
  __shared__ int ws[4];
  __shared__ int sboff;
  if (lane == 63) ws[w] = incl;
  if (t < 64) {
    int partial = 0;
    for (int j = t; j < b; j += 64) partial += bsum[j];
#pragma unroll
    for (int o = 32; o >= 1; o >>= 1) partial += __shfl_xor(partial, o, 64);
    if (t == 0) sboff = partial;
  }
  __syncthreads();
  int wbase = 0;
#pragma unroll
  for (int j = 0; j < 4; j++)
    if (j < w) wbase += ws[j];
  int base = sboff + wbase + incl - s;  // exclusive prefix for idx
  int e0 = base, e1 = e0 + v.x, e2 = e1 + v.y, e3 = e2 + v.z;
  // idx is a multiple of 4; only idx itself can be a multiple of KB.
  if (idx < M) {
    cnt[idx] = e0;
    if ((idx & (KB - 1)) == 0) bsv[idx >> KBSH] = e0;
  }
  if (idx + 1 < M) cnt[idx + 1] = e1;
  if (idx + 2 < M) cnt[idx + 2] = e2;
  if (idx + 3 < M) cnt[idx + 3] = e3;
}

// ph3: scatter edges into bucket-grouped tmp via LDS cursors, 8-deep batched.
__global__ __launch_bounds__(256) void k_scatter(
    const int* __restrict__ src, const int* __restrict__ dst,
    const int* __restrict__ cnt, u32* __restrict__ tmp, int E, int NB,
    int EPB) {
  __shared__ int off[512];
  const int k = blockIdx.x, tid = threadIdx.x;
  for (int b = tid; b < NB; b += 256) off[b] = cnt[b * KB + k];
  __syncthreads();
  const int e0 = k * EPB, e1 = min(E, e0 + EPB);
  for (int base = e0 + tid; base < e1; base += 2048) {
    int dd[8], ss[8];
#pragma unroll
    for (int i = 0; i < 8; i++) {
      int e = base + i * 256;
      dd[i] = (e < e1) ? dst[e] : -1;
      ss[i] = (e < e1) ? src[e] : 0;
    }
#pragma unroll
    for (int i = 0; i < 8; i++) {
      if (dd[i] >= 0) {
        int p = atomicAdd(&off[dd[i] >> NBSH], 1);
        tmp[p] = (u32)ss[i] | ((u32)(dd[i] & (BUCKW - 1)) << 16);
      }
    }
  }
}

// ph4: one block per bucket: fine 128-bin LDS hist + scan -> deg/dinv/meta,
// then dst-sorted csr (entry = src; src < 65536 fits 16 bits).
__global__ __launch_bounds__(256) void k_bucket(
    const u32* __restrict__ tmp, const int* __restrict__ bsv,
    int4* __restrict__ meta, float* __restrict__ dinv,
    u32* __restrict__ csr, int N) {
  __shared__ int hist[BUCKW];
  __shared__ int sc[BUCKW];
  __shared__ int cur[BUCKW];
  const int b = blockIdx.x, tid = threadIdx.x;
  const int s0 = bsv[b], s1 = bsv[b + 1];
  if (tid < BUCKW) hist[tid] = 0;
  __syncthreads();
  for (int base = s0 + tid; base < s1; base += 1024) {
    int tt[4];
#pragma unroll
    for (int i = 0; i < 4; i++) {
      int idx = base + i * 256;
      tt[i] = (idx < s1) ? (int)tmp[idx] : -1;
    }
#pragma unroll
    for (int i = 0; i < 4; i++)
      if (tt[i] >= 0) atomicAdd(&hist[(tt[i] >> 16) & (BUCKW - 1)], 1);
  }
  __syncthreads();
  if (tid < BUCKW) sc[tid] = hist[tid];
  __syncthreads();
#pragma unroll
  for (int o = 1; o < BUCKW; o <<= 1) {
    int t = 0;
    if (tid < BUCKW && tid >= o) t = sc[tid - o];
    __syncthreads();
    if (tid < BUCKW) sc[tid] += t;
    __syncthreads();
  }
  if (tid < BUCKW) {
    int dg = hist[tid];
    int excl = sc[tid] - dg;
    cur[tid] = excl;
    int d = (b << NBSH) + tid;
    if (d < N) {
      float dv = rsqrtf((float)dg + 1.0f);
      meta[d] = make_int4(s0 + excl, dg, __builtin_bit_cast(int, dv), 0);
      dinv[d] = dv;
    }
  }
  __syncthreads();
  for (int base = s0 + tid; base < s1; base += 1024) {
    int tt[4];
#pragma unroll
    for (int i = 0; i < 4; i++) {
      int idx = base + i * 256;
      tt[i] = (idx < s1) ? (int)tmp[idx] : -1;
    }
#pragma unroll
    for (int i = 0; i < 4; i++) {
      if (tt[i] >= 0) {
        int r = atomicAdd(&cur[(tt[i] >> 16) & (BUCKW - 1)], 1);
        csr[s0 + r] = (u32)tt[i] & 0xffffu;
      }
    }
  }
}

// ---------------------------------------------------------------------------
// Gather+LN core — FP8 h rows (128 B), fp32 accumulation.
// Row owned by 16 lanes, uint2 (8 fp8) per lane.
// Weights computed INLINE: w = dinv[src]*dinv[row]. dinv is 200KB ->
// L2-resident; the dinv load issues at the same chase depth as the row
// load (both depend on the csr word), adding no chain length. This
// removes the k_weights pass entirely.
#define ACC_EDGE(vv, ww)                                                     \
  {                                                                          \
    f32x2 p_;                                                                \
    p_ = __builtin_amdgcn_cvt_pk_f32_fp8(vv.x, false);                       \
    acc[0] = fmaf(p_[0], ww, acc[0]); acc[1] = fmaf(p_[1], ww, acc[1]);      \
    p_ = __builtin_amdgcn_cvt_pk_f32_fp8(vv.x, true);                        \
    acc[2] = fmaf(p_[0], ww, acc[2]); acc[3] = fmaf(p_[1], ww, acc[3]);      \
    p_ = __builtin_amdgcn_cvt_pk_f32_fp8(vv.y, false);                       \
    acc[4] = fmaf(p_[0], ww, acc[4]); acc[5] = fmaf(p_[1], ww, acc[5]);      \
    p_ = __builtin_amdgcn_cvt_pk_f32_fp8(vv.y, true);                        \
    acc[6] = fmaf(p_[0], ww, acc[6]); acc[7] = fmaf(p_[1], ww, acc[7]);      \
  }

__device__ __forceinline__ void gather_ln_core(
    const uint2* __restrict__ hb, const int4* __restrict__ meta,
    const u32* __restrict__ csr, const float* __restrict__ dinv,
    const float* __restrict__ b,
    const float* __restrict__ g, const float* __restrict__ bln,
    int row, int n, int sl, float out[8]) {
  const bool valid = row < n;
  const int rc = valid ? row : 0;
  int4 mt = meta[rc];
  int beg = mt.x;
  int cnt = valid ? mt.y : 0;
  float dv = __builtin_bit_cast(float, mt.z);
  float sn = dv * dv;

  float acc[8];
  {
    uint2 su = hb[(size_t)rc * 16 + sl];
    f32x2 p0 = __builtin_amdgcn_cvt_pk_f32_fp8(su.x, false);
    f32x2 p1 = __builtin_amdgcn_cvt_pk_f32_fp8(su.x, true);
    f32x2 p2 = __builtin_amdgcn_cvt_pk_f32_fp8(su.y, false);
    f32x2 p3 = __builtin_amdgcn_cvt_pk_f32_fp8(su.y, true);
    acc[0] = p0[0] * sn; acc[1] = p0[1] * sn;
    acc[2] = p1[0] * sn; acc[3] = p1[1] * sn;
    acc[4] = p2[0] * sn; acc[5] = p2[1] * sn;
    acc[6] = p3[0] * sn; acc[7] = p3[1] * sn;
  }

  // divergent per-group loop: all 16 lanes of a group share cnt.
  for (int j0 = 0; j0 < cnt; j0 += 8) {
    u32 e[8];
#pragma unroll
    for (int jj = 0; jj < 8; jj++) {
      int j = j0 + jj;
      e[jj] = (j < cnt) ? csr[beg + j] : 0u;   // uniform per 16-lane group
    }
    uint2 v[8];
#pragma unroll
    for (int jj = 0; jj < 8; jj++)
      v[jj] = hb[(size_t)e[jj] * 16 + sl];
    float dw[8];
#pragma unroll
    for (int jj = 0; jj < 8; jj++) {
      int j = j0 + jj;
      dw[jj] = (j < cnt) ? dinv[e[jj]] : 0.0f;  // L2-hit, same chase depth
    }
#pragma unroll
    for (int jj = 0; jj < 8; jj++) ACC_EDGE(v[jj], dw[jj] * dv);
  }

  // ---- LayerNorm over 128 cols, 8 per lane across 16 lanes ----
  int d0 = sl * 8;
  float4 bb0 = *(const float4*)(b + d0);
  float4 bb1 = *(const float4*)(b + d0 + 4);
  float a0 = acc[0] + bb0.x, a1 = acc[1] + bb0.y;
  float a2 = acc[2] + bb0.z, a3 = acc[3] + bb0.w;
  float a4 = acc[4] + bb1.x, a5 = acc[5] + bb1.y;
  float a6 = acc[6] + bb1.z, a7 = acc[7] + bb1.w;

  float sum = ((a0 + a1) + (a2 + a3)) + ((a4 + a5) + (a6 + a7));
#pragma unroll
  for (int o = 8; o >= 1; o >>= 1) sum += __shfl_xor(sum, o, 16);
  float mu = sum * (1.0f / 128.0f);
  float e0 = a0 - mu, e1 = a1 - mu, e2 = a2 - mu, e3 = a3 - mu;
  float e4 = a4 - mu, e5 = a5 - mu, e6 = a6 - mu, e7 = a7 - mu;
  float vs = ((e0 * e0 + e1 * e1) + (e2 * e2 + e3 * e3)) +
             ((e4 * e4 + e5 * e5) + (e6 * e6 + e7 * e7));
#pragma unroll
  for (int o = 8; o >= 1; o >>= 1) vs += __shfl_xor(vs, o, 16);
  float inv = rsqrtf(vs * (1.0f / 128.0f) + EPS);

  float4 gg0 = *(const float4*)(g + d0);
  float4 gg1 = *(const float4*)(g + d0 + 4);
  float4 bl0 = *(const float4*)(bln + d0);
  float4 bl1 = *(const float4*)(bln + d0 + 4);
  out[0] = fmaxf(e0 * inv * gg0.x + bl0.x, 0.0f);
  out[1] = fmaxf(e1 * inv * gg0.y + bl0.y, 0.0f);
  out[2] = fmaxf(e2 * inv * gg0.z + bl0.z, 0.0f);
  out[3] = fmaxf(e3 * inv * gg0.w + bl0.w, 0.0f);
  out[4] = fmaxf(e4 * inv * gg1.x + bl1.x, 0.0f);
  out[5] = fmaxf(e5 * inv * gg1.y + bl1.y, 0.0f);
  out[6] = fmaxf(e6 * inv * gg1.z + bl1.z, 0.0f);
  out[7] = fmaxf(e7 * inv * gg1.w + bl1.w, 0.0f);
}

// P6a: pure gather1 + LN + ReLU -> y1 (fp16) in global. No LDS, no barrier,
// 64-VGPR target for 8 waves/SIMD residency (latency-bound random gather).
__global__ __launch_bounds__(256, 8) void k_gather1(
    const uint2* __restrict__ hb, const int4* __restrict__ meta,
    const u32* __restrict__ csr, const float* __restrict__ dinv,
    const float* __restrict__ b, const float* __restrict__ g,
    const float* __restrict__ bln,
    u16* __restrict__ y1, int n) {
  const int tid = threadIdx.x;
  const int sl = tid & 15;
  const int row = blockIdx.x * 16 + (tid >> 4);
  float o[8];
  gather_ln_core(hb, meta, csr, dinv, b, g, bln, row, n, sl, o);
  if (row >= n) return;
  uint4 pk;
  pk.x = ((u32)f2h(o[1]) << 16) | (u32)f2h(o[0]);
  pk.y = ((u32)f2h(o[3]) << 16) | (u32)f2h(o[2]);
  pk.z = ((u32)f2h(o[5]) << 16) | (u32)f2h(o[4]);
  pk.w = ((u32)f2h(o[7]) << 16) | (u32)f2h(o[6]);
  *(uint4*)(y1 + (size_t)row * D + sl * 8) = pk;
}

// P6b: standalone GEMM2: y1 (fp16) @ W2 -> B (h2, fp8).
__global__ __launch_bounds__(256) void k_gemm2(const u16* __restrict__ y1,
                                               const u16* __restrict__ Wt2,
                                               u8* __restrict__ outB, int n) {
  gemm_body<false>(y1, Wt2, outB, n, blockIdx.x);
}

// P7: gather2 + LN + ReLU + residual -> fp32 out. Residual read and final
// store are non-temporal (pure streaming) so 51MB of fp32 traffic doesn't
// evict the B rows from L2.
__global__ __launch_bounds__(256, 8) void k_gather2(
    const uint2* __restrict__ hb, const int4* __restrict__ meta,
    const u32* __restrict__ csr, const float* __restrict__ dinv,
    const float* __restrict__ b, const float* __restrict__ g,
    const float* __restrict__ bln, const float* __restrict__ resid,
    float* __restrict__ outf, int n) {
  const int tid = threadIdx.x;
  const int sl = tid & 15;
  const int row = blockIdx.x * 16 + (tid >> 4);
  float o[8];
  gather_ln_core(hb, meta, csr, dinv, b, g, bln, row, n, sl, o);
  if (row >= n) return;
  size_t base = (size_t)row * D + sl * 8;
  f32x4 r0 = __builtin_nontemporal_load((const f32x4*)(resid + base));
  f32x4 r1 = __builtin_nontemporal_load((const f32x4*)(resid + base + 4));
  f32x4 w0, w1;
  w0[0] = o[0] + r0[0]; w0[1] = o[1] + r0[1];
  w0[2] = o[2] + r0[2]; w0[3] = o[3] + r0[3];
  w1[0] = o[4] + r1[0]; w1[1] = o[5] + r1[1];
  w1[2] = o[6] + r1[2]; w1[3] = o[7] + r1[3];
  __builtin_nontemporal_store(w0, (f32x4*)(outf + base));
  __builtin_nontemporal_store(w1, (f32x4*)(outf + base + 4));
}

// ---------------------------------------------------------------------------
extern "C" void kernel_launch(void* const* d_in, const int* in_sizes, int n_in,
                              void* d_out, int out_size, void* d_ws, size_t ws_size,
                              hipStream_t stream) {
  const float* x    = (const float*)d_in[0];
  const int*   ei   = (const int*)d_in[1];
  const float* W1   = (const float*)d_in[2];
  const float* b1   = (const float*)d_in[3];
  const float* g1   = (const float*)d_in[4];
  const float* bl1  = (const float*)d_in[5];
  const float* W2   = (const float*)d_in[6];
  const float* b2   = (const float*)d_in[7];
  const float* g2   = (const float*)d_in[8];
  const float* bl2  = (const float*)d_in[9];

  const int N = in_sizes[0] / D;
  const int E = in_sizes[1] / 2;
  const int* src = ei;
  const int* dst = ei + E;

  const int NB  = (N + BUCKW - 1) / BUCKW;  // coarse buckets
  const int M   = NB * KB;
  const int EPB = (E + KB - 1) / KB;        // edges per count/scatter block
  const int GB  = (N + 31) / 32;            // gemm blocks (32 rows each)
  const int RB  = (N + 15) / 16;            // gather blocks (16 rows each)
  const int SB  = (M + 1023) / 1024;        // scan blocks

  size_t off = 0;
  auto walloc = [&](size_t bytes) {
    void* p = (char*)d_ws + off;
    off = (off + bytes + 255) & ~(size_t)255;
    return p;
  };
  int*   cnt   = (int*)walloc((size_t)M * 4);
  int*   bsum  = (int*)walloc((size_t)SB * 4);
  int*   bsv   = (int*)walloc((size_t)(NB + 1) * 4);
  u32*   tmp   = (u32*)walloc((size_t)E * 4);
  u32*   csr   = (u32*)walloc((size_t)E * 4);
  int4*  meta  = (int4*)walloc((size_t)N * 16);
  float* dinv  = (float*)walloc((size_t)N * 4);
  u8*    A     = (u8*)walloc((size_t)N * D);        // h1 (fp8 e4m3)
  u8*    B     = (u8*)walloc((size_t)N * D);        // h2 (fp8 e4m3)
  u16*   Wt1   = (u16*)walloc((size_t)D * D * 2);
  u16*   Wt2   = (u16*)walloc((size_t)D * D * 2);
  u16*   y1    = (u16*)walloc((size_t)N * D * 2);   // LN1 out (fp16)
  float* O     = (float*)d_out;

  // P0: weight converts
  k_prep<<<(2 * D * D + 255) / 256, 256, 0, stream>>>(W1, W2, Wt1, Wt2);
  // ph1: coarse count || GEMM1 (x @ W1 -> A fp8)
  k_count_gemm1<<<KB + GB, 256, 0, stream>>>(dst, cnt, E, NB, EPB, x, Wt1, A, N);
  // ph2: parallel scan (reduce -> apply-with-inline-mid)
  k_scan_reduce<<<SB, 256, 0, stream>>>(cnt, M, bsum);
  k_scan_apply<<<SB, 256, 0, stream>>>(cnt, M, bsum, bsv, NB, E);
  // ph3: scatter into buckets
  k_scatter<<<KB, 256, 0, stream>>>(src, dst, cnt, tmp, E, NB, EPB);
  // ph4: per-bucket fine sort -> csr + meta + dinv
  k_bucket<<<NB, 256, 0, stream>>>(tmp, bsv, meta, dinv, csr, N);
  // P6a: gather1 (inline weights) + LN + ReLU -> y1 (fp16)
  k_gather1<<<RB, 256, 0, stream>>>((const uint2*)A, meta, csr, dinv,
                                    b1, g1, bl1, y1, N);
  // P6b: GEMM2 -> B (fp8)
  k_gemm2<<<GB, 256, 0, stream>>>(y1, Wt2, B, N);
  // P7: gather2 (inline weights) + LN + ReLU + residual -> O
  k_gather2<<<RB, 256, 0, stream>>>((const uint2*)B, meta, csr, dinv,
                                    b2, g2, bl2, x, O, N);
}

// Round 14
// 182.708 us; speedup vs baseline: 1.9662x; 1.0334x over previous
//
#include <hip/hip_runtime.h>
#include <hip/hip_fp16.h>

#define D 128
#define EPS 1e-5f
#define KB 256         // coarse count/scatter blocks
#define KBSH 8         // log2(KB)
#define NBSH 7         // bucket = dst >> 7
#define BUCKW 128      // dsts per bucket

typedef unsigned int u32;
typedef unsigned short u16;
typedef unsigned char u8;
typedef __attribute__((ext_vector_type(8))) _Float16 half8;  // mfma A/B frag
typedef __attribute__((ext_vector_type(4))) float f32x4;
typedef __attribute__((ext_vector_type(2))) float f32x2;

__device__ inline u16 f2h(float x) {
  _Float16 t = (_Float16)x;
  return __builtin_bit_cast(u16, t);
}
__device__ inline u8 f2fp8(float x) {
  return (u8)(__builtin_amdgcn_cvt_pk_fp8_f32(x, x, 0, false) & 0xff);
}

// ---------------------------------------------------------------------------
// P0: convert W1,W2 fp32[k][c] -> fp16 Wt[c][k].
__global__ __launch_bounds__(256) void k_prep(const float* __restrict__ W1,
                                              const float* __restrict__ W2,
                                              u16* __restrict__ Wt1,
                                              u16* __restrict__ Wt2) {
  int i = blockIdx.x * 256 + threadIdx.x;
  if (i < 2 * D * D) {
    const float* W = (i < D * D) ? W1 : W2;
    u16* Wt = (i < D * D) ? Wt1 : Wt2;
    int ii = i & (D * D - 1);
    int k = ii >> 7, c = ii & 127;
    Wt[c * D + k] = f2h(W[ii]);
  }
}

// ---------------------------------------------------------------------------
// MFMA GEMM body with LDS staging; OUTPUT IS FP8 (e4m3). 32 rows per block,
// 4 waves = 2 row-halves x 2 ct-halves.
//  - A tile staged global->LDS with coalesced 16-32B/thread linear copies
//    (fp32 converted to fp16 during staging, identical casts as before).
//  - Fragments via ds_read_b128 (272B row stride: 16B-aligned, 4-bank
//    rotation -> <=2-way conflicts, free).
//  - C tile staged as bytes in LDS, written out as one dwordx4 per thread
//    (replaces 1-byte/lane global scatters).
// Values, MFMA order, and row-clamp semantics identical -> bit-identical.
template <bool F32IN>
__device__ __forceinline__ void gemm_body(const void* __restrict__ in_,
                                          const u16* __restrict__ Wt,
                                          u8* __restrict__ out, int nrows,
                                          int blk, u16 (*sA)[136]) {
  const int tid = threadIdx.x;

  // ---- stage A (as fp16) into LDS, coalesced ----
  if (F32IN) {
    const float* in = (const float*)in_;
#pragma unroll
    for (int r = 0; r < 2; r++) {
      int c = tid + r * 256;            // 512 chunks of 8 halves
      int row = c >> 4, col8 = c & 15;
      int rg = min(blk * 32 + row, nrows - 1);
      float4 v0 = *(const float4*)(in + (size_t)rg * D + col8 * 8);
      float4 v1 = *(const float4*)(in + (size_t)rg * D + col8 * 8 + 4);
      half8 h;
      h[0] = (_Float16)v0.x; h[1] = (_Float16)v0.y;
      h[2] = (_Float16)v0.z; h[3] = (_Float16)v0.w;
      h[4] = (_Float16)v1.x; h[5] = (_Float16)v1.y;
      h[6] = (_Float16)v1.z; h[7] = (_Float16)v1.w;
      *(half8*)(&sA[row][col8 * 8]) = h;
    }
  } else {
    const u16* in = (const u16*)in_;
#pragma unroll
    for (int r = 0; r < 2; r++) {
      int c = tid + r * 256;
      int row = c >> 4, col8 = c & 15;
      int rg = min(blk * 32 + row, nrows - 1);
      *(half8*)(&sA[row][col8 * 8]) =
          *(const half8*)(in + (size_t)rg * D + col8 * 8);
    }
  }
  __syncthreads();

  const int lane = tid & 63, wv = tid >> 6;
  const int m = lane & 15, q = lane >> 4;
  const int rl0 = (wv & 1) * 16;               // local row base
  const int ch = wv >> 1;                      // ct = ch*4 + c

  f32x4 acc[4];
#pragma unroll
  for (int c = 0; c < 4; c++) acc[c] = (f32x4)(0.0f);

#pragma unroll
  for (int kk = 0; kk < 4; kk++) {
    const int kbase = kk * 32 + q * 8;
    half8 a = *(const half8*)(&sA[rl0 + m][kbase]);
#pragma unroll
    for (int c = 0; c < 4; c++) {
      int ct = ch * 4 + c;
      half8 b = *(const half8*)(Wt + (ct * 16 + m) * D + kbase);
      acc[c] = __builtin_amdgcn_mfma_f32_16x16x32_f16(a, b, acc[c], 0, 0, 0);
    }
  }
  __syncthreads();

  // ---- stage C tile (fp8 bytes) in LDS: [32][144] ----
  u8* so = (u8*)sA;
#pragma unroll
  for (int c = 0; c < 4; c++) {
    int ct = ch * 4 + c;
#pragma unroll
    for (int rg = 0; rg < 4; rg++) {
      so[(rl0 + q * 4 + rg) * 144 + ct * 16 + m] = f2fp8(acc[c][rg]);
    }
  }
  __syncthreads();

  // ---- coalesced global store: one dwordx4 per thread ----
  {
    int row = tid >> 3, col16 = tid & 7;
    int rr = blk * 32 + row;
    if (rr < nrows) {
      uint4 v = *(const uint4*)(so + row * 144 + col16 * 16);
      *(uint4*)(out + (size_t)rr * D + col16 * 16) = v;
    }
  }
}

// ph1: coarse-bucket count, 8-deep batched (blocks [0,KB)) || GEMM1.
__global__ __launch_bounds__(256) void k_count_gemm1(
    const int* __restrict__ dst, int* __restrict__ cnt, int E, int NB, int EPB,
    const float* __restrict__ x, const u16* __restrict__ Wt1,
    u8* __restrict__ A, int nrows) {
  __shared__ int hist[512];
  __shared__ alignas(16) u16 sA[32][136];
  if (blockIdx.x < (u32)KB) {
    const int k = blockIdx.x, tid = threadIdx.x;
    for (int i = tid; i < NB; i += 256) hist[i] = 0;
    __syncthreads();
    const int e0 = k * EPB, e1 = min(E, e0 + EPB);
    for (int base = e0 + tid; base < e1; base += 2048) {
      int dd[8];
#pragma unroll
      for (int i = 0; i < 8; i++) {
        int e = base + i * 256;
        dd[i] = (e < e1) ? dst[e] : -1;
      }
#pragma unroll
      for (int i = 0; i < 8; i++)
        if (dd[i] >= 0) atomicAdd(&hist[dd[i] >> NBSH], 1);
    }
    __syncthreads();
    for (int b = tid; b < NB; b += 256) cnt[b * KB + k] = hist[b];
  } else {
    gemm_body<true>(x, Wt1, A, nrows, blockIdx.x - KB, sA);
  }
}

// ph2a: per-block (1024 elem) reduce -> bsum.
__global__ __launch_bounds__(256) void k_scan_reduce(
    const int* __restrict__ cnt, int M, int* __restrict__ bsum) {
  const int b = blockIdx.x, t = threadIdx.x;
  const int lane = t & 63, w = t >> 6;
  int idx = b * 1024 + t * 4;
  int4 v = make_int4(0, 0, 0, 0);
  if (idx + 3 < M) {
    v = *(const int4*)(cnt + idx);
  } else {
    if (idx + 0 < M) v.x = cnt[idx + 0];
    if (idx + 1 < M) v.y = cnt[idx + 1];
    if (idx + 2 < M) v.z = cnt[idx + 2];
  }
  int s = v.x + v.y + v.z + v.w;
#pragma unroll
  for (int o = 1; o < 64; o <<= 1) s += __shfl_xor(s, o, 64);
  __shared__ int ws[4];
  if (lane == 0) ws[w] = s;
  __syncthreads();
  if (t == 0) bsum[b] = ws[0] + ws[1] + ws[2] + ws[3];
}

// ph2b: per-block local scan; block offset = sum of bsum[0..b-1] (inline mid).
__global__ __launch_bounds__(256) void k_scan_apply(
    int* __restrict__ cnt, int M, const int* __restrict__ bsum,
    int* __restrict__ bsv, int NB, int E) {
  const int b = blockIdx.x, t = threadIdx.x;
  const int lane = t & 63, w = t >> 6;
  if (b == 0 && t == 0) bsv[NB] = E;
  int idx = b * 1024 + t * 4;
  int4 v = make_int4(0, 0, 0, 0);
  if (idx + 3 < M) {
    v = *(const int4*)(cnt + idx);
  } else {
    if (idx + 0 < M) v.x = cnt[idx + 0];
    if (idx + 1 < M) v.y = cnt[idx + 1];
    if (idx + 2 < M) v.z = cnt[idx + 2];
  }
  int s = v.x + v.y + v.z + v.w;
  int incl = s;
#pragma unroll
  for (int o = 1; o < 64; o <<= 1) {
    int u = __shfl_up(incl, o, 64);
    if (lane >= o) incl += u;
  }
  __shared__ int ws[4];
  __shared__ int sboff;
  if (lane == 63) ws[w] = incl;
  if (t < 64) {
    int partial = 0;
    for (int j = t; j < b; j += 64) partial += bsum[j];
#pragma unroll
    for (int o = 32; o >= 1; o >>= 1) partial += __shfl_xor(partial, o, 64);
    if (t == 0) sboff = partial;
  }
  __syncthreads();
  int wbase = 0;
#pragma unroll
  for (int j = 0; j < 4; j++)
    if (j < w) wbase += ws[j];
  int base = sboff + wbase + incl - s;  // exclusive prefix for idx
  int e0 = base, e1 = e0 + v.x, e2 = e1 + v.y, e3 = e2 + v.z;
  // idx is a multiple of 4; only idx itself can be a multiple of KB.
  if (idx < M) {
    cnt[idx] = e0;
    if ((idx & (KB - 1)) == 0) bsv[idx >> KBSH] = e0;
  }
  if (idx + 1 < M) cnt[idx + 1] = e1;
  if (idx + 2 < M) cnt[idx + 2] = e2;
  if (idx + 3 < M) cnt[idx + 3] = e3;
}

// ph3: scatter edges into bucket-grouped tmp via LDS cursors, 8-deep batched.
__global__ __launch_bounds__(256) void k_scatter(
    const int* __restrict__ src, const int* __restrict__ dst,
    const int* __restrict__ cnt, u32* __restrict__ tmp, int E, int NB,
    int EPB) {
  __shared__ int off[512];
  const int k = blockIdx.x, tid = threadIdx.x;
  for (int b = tid; b < NB; b += 256) off[b] = cnt[b * KB + k];
  __syncthreads();
  const int e0 = k * EPB, e1 = min(E, e0 + EPB);
  for (int base = e0 + tid; base < e1; base += 2048) {
    int dd[8], ss[8];
#pragma unroll
    for (int i = 0; i < 8; i++) {
      int e = base + i * 256;
      dd[i] = (e < e1) ? dst[e] : -1;
      ss[i] = (e < e1) ? src[e] : 0;
    }
#pragma unroll
    for (int i = 0; i < 8; i++) {
      if (dd[i] >= 0) {
        int p = atomicAdd(&off[dd[i] >> NBSH], 1);
        tmp[p] = (u32)ss[i] | ((u32)(dd[i] & (BUCKW - 1)) << 16);
      }
    }
  }
}

// ph4: one block per bucket: fine 128-bin LDS hist + scan -> deg/dinv/meta,
// then dst-sorted csr (entry = src; src < 65536 fits 16 bits).
__global__ __launch_bounds__(256) void k_bucket(
    const u32* __restrict__ tmp, const int* __restrict__ bsv,
    int4* __restrict__ meta, float* __restrict__ dinv,
    u32* __restrict__ csr, int N) {
  __shared__ int hist[BUCKW];
  __shared__ int sc[BUCKW];
  __shared__ int cur[BUCKW];
  const int b = blockIdx.x, tid = threadIdx.x;
  const int s0 = bsv[b], s1 = bsv[b + 1];
  if (tid < BUCKW) hist[tid] = 0;
  __syncthreads();
  for (int base = s0 + tid; base < s1; base += 1024) {
    int tt[4];
#pragma unroll
    for (int i = 0; i < 4; i++) {
      int idx = base + i * 256;
      tt[i] = (idx < s1) ? (int)tmp[idx] : -1;
    }
#pragma unroll
    for (int i = 0; i < 4; i++)
      if (tt[i] >= 0) atomicAdd(&hist[(tt[i] >> 16) & (BUCKW - 1)], 1);
  }
  __syncthreads();
  if (tid < BUCKW) sc[tid] = hist[tid];
  __syncthreads();
#pragma unroll
  for (int o = 1; o < BUCKW; o <<= 1) {
    int t = 0;
    if (tid < BUCKW && tid >= o) t = sc[tid - o];
    __syncthreads();
    if (tid < BUCKW) sc[tid] += t;
    __syncthreads();
  }
  if (tid < BUCKW) {
    int dg = hist[tid];
    int excl = sc[tid] - dg;
    cur[tid] = excl;
    int d = (b << NBSH) + tid;
    if (d < N) {
      float dv = rsqrtf((float)dg + 1.0f);
      meta[d] = make_int4(s0 + excl, dg, __builtin_bit_cast(int, dv), 0);
      dinv[d] = dv;
    }
  }
  __syncthreads();
  for (int base = s0 + tid; base < s1; base += 1024) {
    int tt[4];
#pragma unroll
    for (int i = 0; i < 4; i++) {
      int idx = base + i * 256;
      tt[i] = (idx < s1) ? (int)tmp[idx] : -1;
    }
#pragma unroll
    for (int i = 0; i < 4; i++) {
      if (tt[i] >= 0) {
        int r = atomicAdd(&cur[(tt[i] >> 16) & (BUCKW - 1)], 1);
        csr[s0 + r] = (u32)tt[i] & 0xffffu;
      }
    }
  }
}

// ---------------------------------------------------------------------------
// Gather+LN core — FP8 h rows (128 B), fp32 accumulation.
// Row owned by 16 lanes, uint2 (8 fp8) per lane.
// Weights computed INLINE: w = dinv[src]*dinv[row] (dinv 200KB, L2-hot;
// same chase depth as the row load). Divergent per-group loop bound.
#define ACC_EDGE(vv, ww)                                                     \
  {                                                                          \
    f32x2 p_;                                                                \
    p_ = __builtin_amdgcn_cvt_pk_f32_fp8(vv.x, false);                       \
    acc[0] = fmaf(p_[0], ww, acc[0]); acc[1] = fmaf(p_[1], ww, acc[1]);      \
    p_ = __builtin_amdgcn_cvt_pk_f32_fp8(vv.x, true);                        \
    acc[2] = fmaf(p_[0], ww, acc[2]); acc[3] = fmaf(p_[1], ww, acc[3]);      \
    p_ = __builtin_amdgcn_cvt_pk_f32_fp8(vv.y, false);                       \
    acc[4] = fmaf(p_[0], ww, acc[4]); acc[5] = fmaf(p_[1], ww, acc[5]);      \
    p_ = __builtin_amdgcn_cvt_pk_f32_fp8(vv.y, true);                        \
    acc[6] = fmaf(p_[0], ww, acc[6]); acc[7] = fmaf(p_[1], ww, acc[7]);      \
  }

__device__ __forceinline__ void gather_ln_core(
    const uint2* __restrict__ hb, const int4* __restrict__ meta,
    const u32* __restrict__ csr, const float* __restrict__ dinv,
    const float* __restrict__ b,
    const float* __restrict__ g, const float* __restrict__ bln,
    int row, int n, int sl, float out[8]) {
  const bool valid = row < n;
  const int rc = valid ? row : 0;
  int4 mt = meta[rc];
  int beg = mt.x;
  int cnt = valid ? mt.y : 0;
  float dv = __builtin_bit_cast(float, mt.z);
  float sn = dv * dv;

  float acc[8];
  {
    uint2 su = hb[(size_t)rc * 16 + sl];
    f32x2 p0 = __builtin_amdgcn_cvt_pk_f32_fp8(su.x, false);
    f32x2 p1 = __builtin_amdgcn_cvt_pk_f32_fp8(su.x, true);
    f32x2 p2 = __builtin_amdgcn_cvt_pk_f32_fp8(su.y, false);
    f32x2 p3 = __builtin_amdgcn_cvt_pk_f32_fp8(su.y, true);
    acc[0] = p0[0] * sn; acc[1] = p0[1] * sn;
    acc[2] = p1[0] * sn; acc[3] = p1[1] * sn;
    acc[4] = p2[0] * sn; acc[5] = p2[1] * sn;
    acc[6] = p3[0] * sn; acc[7] = p3[1] * sn;
  }

  // divergent per-group loop: all 16 lanes of a group share cnt.
  for (int j0 = 0; j0 < cnt; j0 += 8) {
    u32 e[8];
#pragma unroll
    for (int jj = 0; jj < 8; jj++) {
      int j = j0 + jj;
      e[jj] = (j < cnt) ? csr[beg + j] : 0u;   // uniform per 16-lane group
    }
    uint2 v[8];
#pragma unroll
    for (int jj = 0; jj < 8; jj++)
      v[jj] = hb[(size_t)e[jj] * 16 + sl];
    float dw[8];
#pragma unroll
    for (int jj = 0; jj < 8; jj++) {
      int j = j0 + jj;
      dw[jj] = (j < cnt) ? dinv[e[jj]] : 0.0f;  // L2-hit, same chase depth
    }
#pragma unroll
    for (int jj = 0; jj < 8; jj++) ACC_EDGE(v[jj], dw[jj] * dv);
  }

  // ---- LayerNorm over 128 cols, 8 per lane across 16 lanes ----
  int d0 = sl * 8;
  float4 bb0 = *(const float4*)(b + d0);
  float4 bb1 = *(const float4*)(b + d0 + 4);
  float a0 = acc[0] + bb0.x, a1 = acc[1] + bb0.y;
  float a2 = acc[2] + bb0.z, a3 = acc[3] + bb0.w;
  float a4 = acc[4] + bb1.x, a5 = acc[5] + bb1.y;
  float a6 = acc[6] + bb1.z, a7 = acc[7] + bb1.w;

  float sum = ((a0 + a1) + (a2 + a3)) + ((a4 + a5) + (a6 + a7));
#pragma unroll
  for (int o = 8; o >= 1; o >>= 1) sum += __shfl_xor(sum, o, 16);
  float mu = sum * (1.0f / 128.0f);
  float e0 = a0 - mu, e1 = a1 - mu, e2 = a2 - mu, e3 = a3 - mu;
  float e4 = a4 - mu, e5 = a5 - mu, e6 = a6 - mu, e7 = a7 - mu;
  float vs = ((e0 * e0 + e1 * e1) + (e2 * e2 + e3 * e3)) +
             ((e4 * e4 + e5 * e5) + (e6 * e6 + e7 * e7));
#pragma unroll
  for (int o = 8; o >= 1; o >>= 1) vs += __shfl_xor(vs, o, 16);
  float inv = rsqrtf(vs * (1.0f / 128.0f) + EPS);

  float4 gg0 = *(const float4*)(g + d0);
  float4 gg1 = *(const float4*)(g + d0 + 4);
  float4 bl0 = *(const float4*)(bln + d0);
  float4 bl1 = *(const float4*)(bln + d0 + 4);
  out[0] = fmaxf(e0 * inv * gg0.x + bl0.x, 0.0f);
  out[1] = fmaxf(e1 * inv * gg0.y + bl0.y, 0.0f);
  out[2] = fmaxf(e2 * inv * gg0.z + bl0.z, 0.0f);
  out[3] = fmaxf(e3 * inv * gg0.w + bl0.w, 0.0f);
  out[4] = fmaxf(e4 * inv * gg1.x + bl1.x, 0.0f);
  out[5] = fmaxf(e5 * inv * gg1.y + bl1.y, 0.0f);
  out[6] = fmaxf(e6 * inv * gg1.z + bl1.z, 0.0f);
  out[7] = fmaxf(e7 * inv * gg1.w + bl1.w, 0.0f);
}

// P6a: pure gather1 + LN + ReLU -> y1 (fp16) in global. No LDS, no barrier,
// 64-VGPR target for 8 waves/SIMD residency (latency-bound random gather).
__global__ __launch_bounds__(256, 8) void k_gather1(
    const uint2* __restrict__ hb, const int4* __restrict__ meta,
    const u32* __restrict__ csr, const float* __restrict__ dinv,
    const float* __restrict__ b, const float* __restrict__ g,
    const float* __restrict__ bln,
    u16* __restrict__ y1, int n) {
  const int tid = threadIdx.x;
  const int sl = tid & 15;
  const int row = blockIdx.x * 16 + (tid >> 4);
  float o[8];
  gather_ln_core(hb, meta, csr, dinv, b, g, bln, row, n, sl, o);
  if (row >= n) return;
  uint4 pk;
  pk.x = ((u32)f2h(o[1]) << 16) | (u32)f2h(o[0]);
  pk.y = ((u32)f2h(o[3]) << 16) | (u32)f2h(o[2]);
  pk.z = ((u32)f2h(o[5]) << 16) | (u32)f2h(o[4]);
  pk.w = ((u32)f2h(o[7]) << 16) | (u32)f2h(o[6]);
  *(uint4*)(y1 + (size_t)row * D + sl * 8) = pk;
}

// P6b: standalone GEMM2: y1 (fp16) @ W2 -> B (h2, fp8).
__global__ __launch_bounds__(256) void k_gemm2(const u16* __restrict__ y1,
                                               const u16* __restrict__ Wt2,
                                               u8* __restrict__ outB, int n) {
  __shared__ alignas(16) u16 sA[32][136];
  gemm_body<false>(y1, Wt2, outB, n, blockIdx.x, sA);
}

// P7: gather2 + LN + ReLU + residual -> fp32 out. Residual read and final
// store are non-temporal (pure streaming) so 51MB of fp32 traffic doesn't
// evict the B rows from L2.
__global__ __launch_bounds__(256, 8) void k_gather2(
    const uint2* __restrict__ hb, const int4* __restrict__ meta,
    const u32* __restrict__ csr, const float* __restrict__ dinv,
    const float* __restrict__ b, const float* __restrict__ g,
    const float* __restrict__ bln, const float* __restrict__ resid,
    float* __restrict__ outf, int n) {
  const int tid = threadIdx.x;
  const int sl = tid & 15;
  const int row = blockIdx.x * 16 + (tid >> 4);
  float o[8];
  gather_ln_core(hb, meta, csr, dinv, b, g, bln, row, n, sl, o);
  if (row >= n) return;
  size_t base = (size_t)row * D + sl * 8;
  f32x4 r0 = __builtin_nontemporal_load((const f32x4*)(resid + base));
  f32x4 r1 = __builtin_nontemporal_load((const f32x4*)(resid + base + 4));
  f32x4 w0, w1;
  w0[0] = o[0] + r0[0]; w0[1] = o[1] + r0[1];
  w0[2] = o[2] + r0[2]; w0[3] = o[3] + r0[3];
  w1[0] = o[4] + r1[0]; w1[1] = o[5] + r1[1];
  w1[2] = o[6] + r1[2]; w1[3] = o[7] + r1[3];
  __builtin_nontemporal_store(w0, (f32x4*)(outf + base));
  __builtin_nontemporal_store(w1, (f32x4*)(outf + base + 4));
}

// ---------------------------------------------------------------------------
extern "C" void kernel_launch(void* const* d_in, const int* in_sizes, int n_in,
                              void* d_out, int out_size, void* d_ws, size_t ws_size,
                              hipStream_t stream) {
  const float* x    = (const float*)d_in[0];
  const int*   ei   = (const int*)d_in[1];
  const float* W1   = (const float*)d_in[2];
  const float* b1   = (const float*)d_in[3];
  const float* g1   = (const float*)d_in[4];
  const float* bl1  = (const float*)d_in[5];
  const float* W2   = (const float*)d_in[6];
  const float* b2   = (const float*)d_in[7];
  const float* g2   = (const float*)d_in[8];
  const float* bl2  = (const float*)d_in[9];

  const int N = in_sizes[0] / D;
  const int E = in_sizes[1] / 2;
  const int* src = ei;
  const int* dst = ei + E;

  const int NB  = (N + BUCKW - 1) / BUCKW;  // coarse buckets
  const int M   = NB * KB;
  const int EPB = (E + KB - 1) / KB;        // edges per count/scatter block
  const int GB  = (N + 31) / 32;            // gemm blocks (32 rows each)
  const int RB  = (N + 15) / 16;            // gather blocks (16 rows each)
  const int SB  = (M + 1023) / 1024;        // scan blocks

  size_t off = 0;
  auto walloc = [&](size_t bytes) {
    void* p = (char*)d_ws + off;
    off = (off + bytes + 255) & ~(size_t)255;
    return p;
  };
  int*   cnt   = (int*)walloc((size_t)M * 4);
  int*   bsum  = (int*)walloc((size_t)SB * 4);
  int*   bsv   = (int*)walloc((size_t)(NB + 1) * 4);
  u32*   tmp   = (u32*)walloc((size_t)E * 4);
  u32*   csr   = (u32*)walloc((size_t)E * 4);
  int4*  meta  = (int4*)walloc((size_t)N * 16);
  float* dinv  = (float*)walloc((size_t)N * 4);
  u8*    A     = (u8*)walloc((size_t)N * D);        // h1 (fp8 e4m3)
  u8*    B     = (u8*)walloc((size_t)N * D);        // h2 (fp8 e4m3)
  u16*   Wt1   = (u16*)walloc((size_t)D * D * 2);
  u16*   Wt2   = (u16*)walloc((size_t)D * D * 2);
  u16*   y1    = (u16*)walloc((size_t)N * D * 2);   // LN1 out (fp16)
  float* O     = (float*)d_out;

  // P0: weight converts
  k_prep<<<(2 * D * D + 255) / 256, 256, 0, stream>>>(W1, W2, Wt1, Wt2);
  // ph1: coarse count || GEMM1 (x @ W1 -> A fp8)
  k_count_gemm1<<<KB + GB, 256, 0, stream>>>(dst, cnt, E, NB, EPB, x, Wt1, A, N);
  // ph2: parallel scan (reduce -> apply-with-inline-mid)
  k_scan_reduce<<<SB, 256, 0, stream>>>(cnt, M, bsum);
  k_scan_apply<<<SB, 256, 0, stream>>>(cnt, M, bsum, bsv, NB, E);
  // ph3: scatter into buckets
  k_scatter<<<KB, 256, 0, stream>>>(src, dst, cnt, tmp, E, NB, EPB);
  // ph4: per-bucket fine sort -> csr + meta + dinv
  k_bucket<<<NB, 256, 0, stream>>>(tmp, bsv, meta, dinv, csr, N);
  // P6a: gather1 (inline weights) + LN + ReLU -> y1 (fp16)
  k_gather1<<<RB, 256, 0, stream>>>((const uint2*)A, meta, csr, dinv,
                                    b1, g1, bl1, y1, N);
  // P6b: GEMM2 -> B (fp8)
  k_gemm2<<<GB, 256, 0, stream>>>(y1, Wt2, B, N);
  // P7: gather2 (inline weights) + LN + ReLU + residual -> O
  k_gather2<<<RB, 256, 0, stream>>>((const uint2*)B, meta, csr, dinv,
                                    b2, g2, bl2, x, O, N);
}